// Round 10
// baseline (159.634 us; speedup 1.0000x reference)
//
#include <hip/hip_runtime.h>

#define EPS 1e-5f
#define TOKS 4096
#define NCF 8192
#define CCH 2048
#define WS_NEED ((size_t)8 * 32 * 8192 * 2)        // 4 MB bf16 phiT' (w folded in)

typedef __attribute__((ext_vector_type(8))) short bf16x8;
typedef __attribute__((ext_vector_type(4))) float f32x4;

__device__ __forceinline__ unsigned short f2bf(float f) {
  unsigned int u = __float_as_uint(f);
  u += 0x7FFFu + ((u >> 16) & 1u);
  return (unsigned short)(u >> 16);
}
__device__ __forceinline__ float bf2f(unsigned short s) {
  return __uint_as_float(((unsigned int)s) << 16);
}

// ---------------- K0: phiT'[a][r][f] = w[a][f] * phi_r[a][f]  (bf16, [A][32][8192]) ----------------
// rows 0-3 = pre cols, 4-7 = post cols, 8-23 = res cols, 24-31 = zero
__global__ __launch_bounds__(256)
void prep_phiT(const float* __restrict__ pre, const float* __restrict__ post,
               const float* __restrict__ res, const float* __restrict__ wnorm,
               unsigned short* __restrict__ phiT) {
  const int gid = blockIdx.x * 256 + threadIdx.x;   // 8*32*1024
  const int a = gid >> 15;
  const int r = (gid >> 10) & 31;
  const int f = (gid & 1023) * 8;
  const float4 wA = *(const float4*)(wnorm + (size_t)a * NCF + f);
  const float4 wB = *(const float4*)(wnorm + (size_t)a * NCF + f + 4);
  const float wv[8] = { wA.x, wA.y, wA.z, wA.w, wB.x, wB.y, wB.z, wB.w };
  unsigned int w[4];
  #pragma unroll
  for (int p = 0; p < 4; ++p) {
    float v0 = 0.f, v1 = 0.f;
    const int e0 = f + 2 * p, e1 = f + 2 * p + 1;
    if (r < 4) {
      v0 = pre[((size_t)a * NCF + e0) * 4 + r];
      v1 = pre[((size_t)a * NCF + e1) * 4 + r];
    } else if (r < 8) {
      v0 = post[((size_t)a * NCF + e0) * 4 + (r - 4)];
      v1 = post[((size_t)a * NCF + e1) * 4 + (r - 4)];
    } else if (r < 24) {
      v0 = res[((size_t)a * NCF + e0) * 16 + (r - 8)];
      v1 = res[((size_t)a * NCF + e1) * 16 + (r - 8)];
    }
    v0 *= wv[2 * p];
    v1 *= wv[2 * p + 1];
    w[p] = (unsigned int)f2bf(v0) | ((unsigned int)f2bf(v1) << 16);
  }
  *(uint4*)(phiT + ((size_t)a * 32 + r) * NCF + f) = make_uint4(w[0], w[1], w[2], w[3]);
}

// ---------------- fused: round-6 K1 skeleton + register-local epilogue ----------------
// 256 blocks x 512 threads (8 waves), 16 tokens/block. Wave w owns K-columns
// { n*2048 + w*256 + d : n=0..3, d=0..255 } (valid permutation of K).
// Each lane keeps its 4-col x slice for all 16 tokens in registers (xsav) ->
// epilogue writes output columns w*256 + lane*4 .. +3 with NO cross-wave x traffic.
__global__ __launch_bounds__(512)
void lora_fused16(const float* __restrict__ x,
                  const float* __restrict__ outp,
                  const unsigned short* __restrict__ phiT,
                  const float* __restrict__ b_pre, const float* __restrict__ b_post,
                  const float* __restrict__ b_res,
                  const float* __restrict__ a_pre, const float* __restrict__ a_post,
                  const float* __restrict__ a_res,
                  const int* __restrict__ aidx_arr,
                  float* __restrict__ agg, float* __restrict__ big) {
  __shared__ unsigned short xs[8][16 * 264];   // per-wave staging tile [16 tok][256], pad 264
  __shared__ float logits_s[8][16][32];
  __shared__ float ssq_s[8][16];
  __shared__ float gates_s[16][24];

  const int tid = threadIdx.x;
  const int wave = tid >> 6, lane = tid & 63;
  const int tok0 = blockIdx.x * 16;
  const int aidx = aidx_arr[tok0 >> 10];
  const int cbase = wave * 256 + lane * 4;     // this lane's column group (per n-chunk)

  const float* xbase = x + (size_t)tok0 * NCF + cbase;
  const unsigned short* pBbase =
      phiT + ((size_t)aidx * 32 + (lane & 15)) * NCF + wave * 256 + (lane >> 4) * 8;

  f32x4 acc0 = {0.f, 0.f, 0.f, 0.f};
  f32x4 acc1 = {0.f, 0.f, 0.f, 0.f};
  float ssq[16];
  #pragma unroll
  for (int r = 0; r < 16; ++r) ssq[r] = 0.f;

  uint2 xsav[16][4];                            // packed bf16 x, [token][n-chunk]

  float4 xr[16];
  #pragma unroll
  for (int r = 0; r < 16; ++r) xr[r] = *(const float4*)(xbase + (size_t)r * NCF);

  for (int n = 0; n < 4; ++n) {
    // stage: ssq + bf16(x) -> LDS tile + register save (wave-private, round-6 pattern)
    #pragma unroll
    for (int r = 0; r < 16; ++r) {
      const float4 v = xr[r];
      ssq[r] += v.x * v.x + v.y * v.y + v.z * v.z + v.w * v.w;
      const unsigned int lo = (unsigned int)f2bf(v.x) | ((unsigned int)f2bf(v.y) << 16);
      const unsigned int hi = (unsigned int)f2bf(v.z) | ((unsigned int)f2bf(v.w) << 16);
      xsav[r][n] = make_uint2(lo, hi);
      *(uint2*)&xs[wave][r * 264 + lane * 4] = make_uint2(lo, hi);
    }
    if (n < 3) {
      #pragma unroll
      for (int r = 0; r < 16; ++r)
        xr[r] = *(const float4*)(xbase + (size_t)r * NCF + (n + 1) * 2048);
    }
    const unsigned short* pB = pBbase + n * 2048;
    #pragma unroll
    for (int s = 0; s < 8; ++s) {
      bf16x8 a = *(const bf16x8*)&xs[wave][(lane & 15) * 264 + s * 32 + (lane >> 4) * 8];
      bf16x8 b0 = *(const bf16x8*)(pB + s * 32);
      bf16x8 b1 = *(const bf16x8*)(pB + 16 * NCF + s * 32);
      acc0 = __builtin_amdgcn_mfma_f32_16x16x32_bf16(a, b0, acc0, 0, 0, 0);
      acc1 = __builtin_amdgcn_mfma_f32_16x16x32_bf16(a, b1, acc1, 0, 0, 0);
    }
  }

  // ssq reduce across 64 lanes
  #pragma unroll
  for (int r = 0; r < 16; ++r) {
    float v = ssq[r];
    #pragma unroll
    for (int m = 1; m <= 32; m <<= 1) v += __shfl_xor(v, m, 64);
    if (lane == 0) ssq_s[wave][r] = v;
  }
  // C frags -> LDS: D[m=tok][n=col], col=lane&15, row=(lane>>4)*4+i (round-6 verbatim)
  #pragma unroll
  for (int i = 0; i < 4; ++i) {
    logits_s[wave][(lane >> 4) * 4 + i][lane & 15] = acc0[i];
    logits_s[wave][(lane >> 4) * 4 + i][16 + (lane & 15)] = acc1[i];
  }
  __syncthreads();

  // ---- gates: sigmoids + Sinkhorn (round-6 verbatim, writes to LDS) ----
  if (tid < 256) {
    const int tok = tid >> 4, cl = tid & 15;
    float L0 = 0.f, L16 = 0.f, ssqt = 0.f;
    #pragma unroll
    for (int w = 0; w < 8; ++w) {
      L0 += logits_s[w][tok][cl];
      L16 += logits_s[w][tok][16 + cl];
      ssqt += ssq_s[w][tok];
    }
    const float invr = rsqrtf(ssqt * (1.f / NCF) + EPS);

    if (cl < 4) {
      const float zp = a_pre[aidx] * L0 * invr + b_pre[(size_t)aidx * 4 + cl];
      gates_s[tok][cl] = 1.f / (1.f + __expf(-zp));
    } else if (cl < 8) {
      const float zq = a_post[aidx] * L0 * invr + b_post[(size_t)aidx * 4 + (cl - 4)];
      gates_s[tok][cl] = 2.f / (1.f + __expf(-zq));
    }
    // res logit l = cl lives in col 8+cl (cols 8-15: L0 block; 16-23: L16 block)
    const float resv = __shfl_xor((cl & 8) ? L0 : L16, 8, 64);
    const float tl = a_res[aidx] * resv * invr + b_res[(size_t)aidx * 16 + cl];
    float m = __expf(tl);
    #pragma unroll
    for (int it = 0; it < 20; ++it) {
      float rs = m;
      rs += __shfl_xor(rs, 1, 64);
      rs += __shfl_xor(rs, 2, 64);
      m *= __builtin_amdgcn_rcpf(rs);
      float cs = m;
      cs += __shfl_xor(cs, 4, 64);
      cs += __shfl_xor(cs, 8, 64);
      m *= __builtin_amdgcn_rcpf(cs);
    }
    gates_s[tok][8 + cl] = m;
  }
  __syncthreads();

  // ---- epilogue: outputs from registers (columns cbase..cbase+3 of every n) ----
  #pragma unroll
  for (int r = 0; r < 16; ++r) {
    const int gtok = tok0 + r;
    const float hp0 = gates_s[r][0], hp1 = gates_s[r][1],
                hp2 = gates_s[r][2], hp3 = gates_s[r][3];
    const float hq[4] = { gates_s[r][4], gates_s[r][5], gates_s[r][6], gates_s[r][7] };
    float M[16];
    #pragma unroll
    for (int i = 0; i < 16; ++i) M[i] = gates_s[r][8 + i];

    float4 xw[4];
    #pragma unroll
    for (int j = 0; j < 4; ++j) {
      const uint2 p = xsav[r][j];
      xw[j] = make_float4(bf2f((unsigned short)(p.x & 0xffff)),
                          bf2f((unsigned short)(p.x >> 16)),
                          bf2f((unsigned short)(p.y & 0xffff)),
                          bf2f((unsigned short)(p.y >> 16)));
    }
    const float4 ov = *(const float4*)(outp + (size_t)gtok * CCH + cbase);

    f32x4 ag;
    ag.x = hp0*xw[0].x + hp1*xw[1].x + hp2*xw[2].x + hp3*xw[3].x;
    ag.y = hp0*xw[0].y + hp1*xw[1].y + hp2*xw[2].y + hp3*xw[3].y;
    ag.z = hp0*xw[0].z + hp1*xw[1].z + hp2*xw[2].z + hp3*xw[3].z;
    ag.w = hp0*xw[0].w + hp1*xw[1].w + hp2*xw[2].w + hp3*xw[3].w;
    __builtin_nontemporal_store(ag, (f32x4*)(agg + (size_t)gtok * CCH + cbase));

    float* brow = big + (size_t)gtok * NCF + cbase;
    #pragma unroll
    for (int i = 0; i < 4; ++i) {
      const float m0 = M[i*4+0], m1 = M[i*4+1], m2 = M[i*4+2], m3 = M[i*4+3];
      f32x4 o;
      o.x = m0*xw[0].x + m1*xw[1].x + m2*xw[2].x + m3*xw[3].x + hq[i]*ov.x;
      o.y = m0*xw[0].y + m1*xw[1].y + m2*xw[2].y + m3*xw[3].y + hq[i]*ov.y;
      o.z = m0*xw[0].z + m1*xw[1].z + m2*xw[2].z + m3*xw[3].z + hq[i]*ov.z;
      o.w = m0*xw[0].w + m1*xw[1].w + m2*xw[2].w + m3*xw[3].w + hq[i]*ov.w;
      __builtin_nontemporal_store(o, (f32x4*)(brow + (size_t)i * CCH));
    }
  }
}

// ---------------- fallback: round-1 fused kernel (used if ws too small) ----------------
__global__ __launch_bounds__(256, 4)
void lora_fused(const float* __restrict__ x, const float* __restrict__ outp,
                const float* __restrict__ wnorm, const float* __restrict__ phi_pre,
                const float* __restrict__ phi_post, const float* __restrict__ phi_res,
                const float* __restrict__ b_pre, const float* __restrict__ b_post,
                const float* __restrict__ b_res, const float* __restrict__ a_pre,
                const float* __restrict__ a_post, const float* __restrict__ a_res,
                const int* __restrict__ aidx_arr, float* __restrict__ agg_out,
                float* __restrict__ big_out) {
  __shared__ unsigned short xsb[2][NCF];
  __shared__ float scratch[4][52];
  __shared__ float red[52];
  __shared__ float Hpre[2][4], Hpost[2][4], Msm[2][16];
  const int tid = threadIdx.x;
  const int tok0 = blockIdx.x * 2;
  const int aidx = aidx_arr[tok0 >> 10];
  const float* xr0 = x + (size_t)tok0 * NCF;
  const float* xr1 = xr0 + NCF;
  const float* wr = wnorm + (size_t)aidx * NCF;
  const float* pp = phi_pre + (size_t)aidx * NCF * 4;
  const float* pq = phi_post + (size_t)aidx * NCF * 4;
  const float* pr = phi_res + (size_t)aidx * NCF * 16;
  float acc[50];
  #pragma unroll
  for (int i = 0; i < 50; ++i) acc[i] = 0.f;
  for (int k = 0; k < 8; ++k) {
    const int f0 = (k * 256 + tid) * 4;
    const float4 w4 = *(const float4*)(wr + f0);
    const float4 xa = *(const float4*)(xr0 + f0);
    const float4 xb = *(const float4*)(xr1 + f0);
    acc[0] += xa.x*xa.x + xa.y*xa.y + xa.z*xa.z + xa.w*xa.w;
    acc[25] += xb.x*xb.x + xb.y*xb.y + xb.z*xb.z + xb.w*xb.w;
    float xw0[4] = { xa.x*w4.x, xa.y*w4.y, xa.z*w4.z, xa.w*w4.w };
    float xw1[4] = { xb.x*w4.x, xb.y*w4.y, xb.z*w4.z, xb.w*w4.w };
    *(ushort4*)&xsb[0][f0] = make_ushort4(f2bf(xa.x), f2bf(xa.y), f2bf(xa.z), f2bf(xa.w));
    *(ushort4*)&xsb[1][f0] = make_ushort4(f2bf(xb.x), f2bf(xb.y), f2bf(xb.z), f2bf(xb.w));
    #pragma unroll
    for (int d = 0; d < 4; ++d) {
      const int f = f0 + d;
      const float a0 = xw0[d], a1 = xw1[d];
      float col[24];
      const float4 P = *(const float4*)(pp + ((size_t)f << 2));
      const float4 Q = *(const float4*)(pq + ((size_t)f << 2));
      const float4 R0 = *(const float4*)(pr + ((size_t)f << 4));
      const float4 R1 = *(const float4*)(pr + ((size_t)f << 4) + 4);
      const float4 R2 = *(const float4*)(pr + ((size_t)f << 4) + 8);
      const float4 R3 = *(const float4*)(pr + ((size_t)f << 4) + 12);
      col[0]=P.x; col[1]=P.y; col[2]=P.z; col[3]=P.w;
      col[4]=Q.x; col[5]=Q.y; col[6]=Q.z; col[7]=Q.w;
      col[8]=R0.x; col[9]=R0.y; col[10]=R0.z; col[11]=R0.w;
      col[12]=R1.x; col[13]=R1.y; col[14]=R1.z; col[15]=R1.w;
      col[16]=R2.x; col[17]=R2.y; col[18]=R2.z; col[19]=R2.w;
      col[20]=R3.x; col[21]=R3.y; col[22]=R3.z; col[23]=R3.w;
      #pragma unroll
      for (int c = 0; c < 24; ++c) { acc[1 + c] += a0 * col[c]; acc[26 + c] += a1 * col[c]; }
    }
  }
  #pragma unroll
  for (int m = 1; m <= 32; m <<= 1) {
    #pragma unroll
    for (int v = 0; v < 50; ++v) acc[v] += __shfl_xor(acc[v], m, 64);
  }
  const int wave = tid >> 6, lane = tid & 63;
  if (lane == 0) {
    #pragma unroll
    for (int v = 0; v < 50; ++v) scratch[wave][v] = acc[v];
  }
  __syncthreads();
  if (tid < 50) red[tid] = scratch[0][tid] + scratch[1][tid] + scratch[2][tid] + scratch[3][tid];
  __syncthreads();
  if (tid < 32) {
    const int t = tid >> 4, l = tid & 15;
    const float invr = rsqrtf(red[t * 25] * (1.f / NCF) + EPS);
    const float tl = a_res[aidx] * red[t * 25 + 1 + 8 + l] * invr + b_res[(size_t)aidx * 16 + l];
    float m = __expf(tl);
    #pragma unroll
    for (int it = 0; it < 20; ++it) {
      float rs = m; rs += __shfl_xor(rs, 1, 64); rs += __shfl_xor(rs, 2, 64);
      m *= __builtin_amdgcn_rcpf(rs);
      float cs = m; cs += __shfl_xor(cs, 4, 64); cs += __shfl_xor(cs, 8, 64);
      m *= __builtin_amdgcn_rcpf(cs);
    }
    Msm[t][l] = m;
  } else if (tid < 40) {
    const int q = tid - 32, t = q >> 2, n = q & 3;
    const float invr = rsqrtf(red[t * 25] * (1.f / NCF) + EPS);
    const float zp = a_pre[aidx] * red[t * 25 + 1 + n] * invr + b_pre[(size_t)aidx * 4 + n];
    const float zq = a_post[aidx] * red[t * 25 + 1 + 4 + n] * invr + b_post[(size_t)aidx * 4 + n];
    Hpre[t][n] = 1.f / (1.f + __expf(-zp));
    Hpost[t][n] = 2.f / (1.f + __expf(-zq));
  }
  __syncthreads();
  #pragma unroll
  for (int t = 0; t < 2; ++t) {
    const int tok = tok0 + t;
    const float* orow = outp + (size_t)tok * CCH;
    float* arow = agg_out + (size_t)tok * CCH;
    float* brow = big_out + (size_t)tok * 4 * CCH;
    const float hp0 = Hpre[t][0], hp1 = Hpre[t][1], hp2 = Hpre[t][2], hp3 = Hpre[t][3];
    float Mr[16];
    #pragma unroll
    for (int i = 0; i < 16; ++i) Mr[i] = Msm[t][i];
    const float hq[4] = { Hpost[t][0], Hpost[t][1], Hpost[t][2], Hpost[t][3] };
    #pragma unroll
    for (int w = 0; w < 2; ++w) {
      const int c0 = (w * 256 + tid) * 4;
      float4 xv[4];
      #pragma unroll
      for (int n = 0; n < 4; ++n) {
        const ushort4 u = *(const ushort4*)&xsb[t][n * CCH + c0];
        xv[n] = make_float4(bf2f(u.x), bf2f(u.y), bf2f(u.z), bf2f(u.w));
      }
      const float4 ov = *(const float4*)(orow + c0);
      float4 ag;
      ag.x = hp0*xv[0].x + hp1*xv[1].x + hp2*xv[2].x + hp3*xv[3].x;
      ag.y = hp0*xv[0].y + hp1*xv[1].y + hp2*xv[2].y + hp3*xv[3].y;
      ag.z = hp0*xv[0].z + hp1*xv[1].z + hp2*xv[2].z + hp3*xv[3].z;
      ag.w = hp0*xv[0].w + hp1*xv[1].w + hp2*xv[2].w + hp3*xv[3].w;
      *(float4*)(arow + c0) = ag;
      #pragma unroll
      for (int i = 0; i < 4; ++i) {
        const float m0 = Mr[i*4+0], m1 = Mr[i*4+1], m2 = Mr[i*4+2], m3 = Mr[i*4+3];
        float4 o;
        o.x = m0*xv[0].x + m1*xv[1].x + m2*xv[2].x + m3*xv[3].x + hq[i]*ov.x;
        o.y = m0*xv[0].y + m1*xv[1].y + m2*xv[2].y + m3*xv[3].y + hq[i]*ov.y;
        o.z = m0*xv[0].z + m1*xv[1].z + m2*xv[2].z + m3*xv[3].z + hq[i]*ov.z;
        o.w = m0*xv[0].w + m1*xv[1].w + m2*xv[2].w + m3*xv[3].w + hq[i]*ov.w;
        *(float4*)(brow + (size_t)i * CCH + c0) = o;
      }
    }
  }
}

extern "C" void kernel_launch(void* const* d_in, const int* in_sizes, int n_in,
                              void* d_out, int out_size, void* d_ws, size_t ws_size,
                              hipStream_t stream) {
  const float* x     = (const float*)d_in[0];
  const float* outp  = (const float*)d_in[1];
  const float* wnorm = (const float*)d_in[2];
  const float* ppre  = (const float*)d_in[3];
  const float* ppost = (const float*)d_in[4];
  const float* pres  = (const float*)d_in[5];
  const float* bpre  = (const float*)d_in[6];
  const float* bpost = (const float*)d_in[7];
  const float* bres  = (const float*)d_in[8];
  const float* apre  = (const float*)d_in[9];
  const float* apost = (const float*)d_in[10];
  const float* ares  = (const float*)d_in[11];
  const int*   aidx  = (const int*)d_in[12];

  float* agg = (float*)d_out;
  float* big = (float*)d_out + (size_t)TOKS * CCH;

  if (ws_size >= WS_NEED) {
    unsigned short* phiT = (unsigned short*)d_ws;
    hipLaunchKernelGGL(prep_phiT, dim3(1024), dim3(256), 0, stream,
                       ppre, ppost, pres, wnorm, phiT);
    hipLaunchKernelGGL(lora_fused16, dim3(256), dim3(512), 0, stream,
                       x, outp, phiT, bpre, bpost, bres, apre, apost, ares, aidx, agg, big);
  } else {
    hipLaunchKernelGGL(lora_fused, dim3(2048), dim3(256), 0, stream,
                       x, outp, wnorm, ppre, ppost, pres,
                       bpre, bpost, bres, apre, apost, ares, aidx, agg, big);
  }
}

// Round 11
// 149.769 us; speedup vs baseline: 1.0659x; 1.0659x over previous
//
#include <hip/hip_runtime.h>

#define EPS 1e-5f
#define TOKS 4096
#define NCF 8192
#define CCH 2048

#define PHI_BYTES ((size_t)8 * 32 * 8192 * 2)            // 4 MB bf16 phiT'
#define LOGP_OFF  PHI_BYTES                              // float[512][16][32] = 1 MB
#define SSQP_OFF  (LOGP_OFF + (size_t)512 * 16 * 32 * 4) // float[512][16] = 32 KB
#define GATES_OFF (SSQP_OFF + (size_t)512 * 16 * 4)      // float[4096][32] = 512 KB
#define WS_NEED   (GATES_OFF + (size_t)TOKS * 32 * 4)

typedef __attribute__((ext_vector_type(8))) short bf16x8;
typedef __attribute__((ext_vector_type(4))) float f32x4;

__device__ __forceinline__ unsigned short f2bf(float f) {
  unsigned int u = __float_as_uint(f);
  u += 0x7FFFu + ((u >> 16) & 1u);
  return (unsigned short)(u >> 16);
}
__device__ __forceinline__ float bf2f(unsigned short s) {
  return __uint_as_float(((unsigned int)s) << 16);
}

// ---------------- K0: phiT'[a][r][f] = w[a][f] * phi_r[a][f]  (bf16, [A][32][8192]) ----------------
// rows 0-3 = pre cols, 4-7 = post cols, 8-23 = res cols, 24-31 = zero   [r10-proven]
__global__ __launch_bounds__(256)
void prep_phiT(const float* __restrict__ pre, const float* __restrict__ post,
               const float* __restrict__ res, const float* __restrict__ wnorm,
               unsigned short* __restrict__ phiT) {
  const int gid = blockIdx.x * 256 + threadIdx.x;   // 8*32*1024
  const int a = gid >> 15;
  const int r = (gid >> 10) & 31;
  const int f = (gid & 1023) * 8;
  const float4 wA = *(const float4*)(wnorm + (size_t)a * NCF + f);
  const float4 wB = *(const float4*)(wnorm + (size_t)a * NCF + f + 4);
  const float wv[8] = { wA.x, wA.y, wA.z, wA.w, wB.x, wB.y, wB.z, wB.w };
  unsigned int w[4];
  #pragma unroll
  for (int p = 0; p < 4; ++p) {
    float v0 = 0.f, v1 = 0.f;
    const int e0 = f + 2 * p, e1 = f + 2 * p + 1;
    if (r < 4) {
      v0 = pre[((size_t)a * NCF + e0) * 4 + r];
      v1 = pre[((size_t)a * NCF + e1) * 4 + r];
    } else if (r < 8) {
      v0 = post[((size_t)a * NCF + e0) * 4 + (r - 4)];
      v1 = post[((size_t)a * NCF + e1) * 4 + (r - 4)];
    } else if (r < 24) {
      v0 = res[((size_t)a * NCF + e0) * 16 + (r - 8)];
      v1 = res[((size_t)a * NCF + e1) * 16 + (r - 8)];
    }
    v0 *= wv[2 * p];
    v1 *= wv[2 * p + 1];
    w[p] = (unsigned int)f2bf(v0) | ((unsigned int)f2bf(v1) << 16);
  }
  *(uint4*)(phiT + ((size_t)a * 32 + r) * NCF + f) = make_uint4(w[0], w[1], w[2], w[3]);
}

// ---------------- K1: split-K logits. grid 512 = (tile 0..255, K-half 0..1) ----------------
// 512 threads = 8 waves; wave w owns cols [koff + w*512, +512) (2 t-iters of 256).
// LDS ~69.7 KB -> 2 blocks/CU.  Cross-wave reduce via LDS atomicAdd; partials -> ws.
__global__ __launch_bounds__(512, 4)
void logits_partial(const float* __restrict__ x,
                    const unsigned short* __restrict__ phiT,
                    const int* __restrict__ aidx_arr,
                    float* __restrict__ logP,    // [512][16][32]
                    float* __restrict__ ssqP) {  // [512][16]
  __shared__ unsigned short xs[8][16 * 264];   // per-wave staging tile (r6-proven pattern)
  __shared__ float logAcc[16][32];
  __shared__ float ssqAcc[16];

  const int tid = threadIdx.x;
  const int wave = tid >> 6, lane = tid & 63;
  const int tile = blockIdx.x >> 1;
  const int h = blockIdx.x & 1;
  const int tok0 = tile * 16;
  const int koff = h * 4096;
  const int aidx = aidx_arr[tok0 >> 10];

  // init accumulators
  if (tid < 512) logAcc[tid >> 5][tid & 31] = 0.f;
  if (tid < 16) ssqAcc[tid] = 0.f;
  __syncthreads();

  const float* xbase = x + (size_t)tok0 * NCF + koff + wave * 512 + lane * 4;
  const unsigned short* pBbase =
      phiT + ((size_t)aidx * 32 + (lane & 15)) * NCF + koff + wave * 512 + (lane >> 4) * 8;

  f32x4 acc0 = {0.f, 0.f, 0.f, 0.f};
  f32x4 acc1 = {0.f, 0.f, 0.f, 0.f};
  float ssq[16];
  #pragma unroll
  for (int r = 0; r < 16; ++r) ssq[r] = 0.f;

  for (int t = 0; t < 2; ++t) {
    float4 xv[16];
    #pragma unroll
    for (int r = 0; r < 16; ++r)
      xv[r] = *(const float4*)(xbase + (size_t)r * NCF + t * 256);
    #pragma unroll
    for (int r = 0; r < 16; ++r) {
      const float4 v = xv[r];
      ssq[r] += v.x * v.x + v.y * v.y + v.z * v.z + v.w * v.w;
      *(ushort4*)&xs[wave][r * 264 + lane * 4] =
          make_ushort4(f2bf(v.x), f2bf(v.y), f2bf(v.z), f2bf(v.w));
    }
    const unsigned short* pB = pBbase + t * 256;
    #pragma unroll
    for (int s = 0; s < 8; ++s) {
      bf16x8 a = *(const bf16x8*)&xs[wave][(lane & 15) * 264 + s * 32 + (lane >> 4) * 8];
      bf16x8 b0 = *(const bf16x8*)(pB + s * 32);
      bf16x8 b1 = *(const bf16x8*)(pB + 16 * NCF + s * 32);
      acc0 = __builtin_amdgcn_mfma_f32_16x16x32_bf16(a, b0, acc0, 0, 0, 0);
      acc1 = __builtin_amdgcn_mfma_f32_16x16x32_bf16(a, b1, acc1, 0, 0, 0);
    }
  }

  // ssq: shuffle-reduce then one atomic per (wave,row)
  #pragma unroll
  for (int r = 0; r < 16; ++r) {
    float v = ssq[r];
    #pragma unroll
    for (int m = 1; m <= 32; m <<= 1) v += __shfl_xor(v, m, 64);
    if (lane == 0) atomicAdd(&ssqAcc[r], v);
  }
  // C frags: D row=(lane>>4)*4+i, col=lane&15  [r6/r10-proven mapping]
  #pragma unroll
  for (int i = 0; i < 4; ++i) {
    atomicAdd(&logAcc[(lane >> 4) * 4 + i][lane & 15], acc0[i]);
    atomicAdd(&logAcc[(lane >> 4) * 4 + i][16 + (lane & 15)], acc1[i]);
  }
  __syncthreads();

  // write partials
  if (tid < 512) logP[(size_t)blockIdx.x * 512 + tid] = logAcc[tid >> 5][tid & 31];
  if (tid < 16) ssqP[(size_t)blockIdx.x * 16 + tid] = ssqAcc[tid];
}

// ---------------- K2: combine halves + sigmoids + Sinkhorn -> gates[tok][32] ----------------
__global__ __launch_bounds__(256)
void gates_kernel(const float* __restrict__ logP, const float* __restrict__ ssqP,
                  const float* __restrict__ b_pre, const float* __restrict__ b_post,
                  const float* __restrict__ b_res,
                  const float* __restrict__ a_pre, const float* __restrict__ a_post,
                  const float* __restrict__ a_res,
                  const int* __restrict__ aidx_arr,
                  float* __restrict__ gates) {
  const int tile = blockIdx.x;
  const int tid = threadIdx.x;
  const int tok = tid >> 4, cl = tid & 15;
  const int tok0 = tile * 16;
  const int aidx = aidx_arr[tok0 >> 10];

  const float* p0 = logP + (size_t)(tile * 2) * 512 + tok * 32;
  const float* p1 = logP + (size_t)(tile * 2 + 1) * 512 + tok * 32;
  const float Lg   = p0[cl] + p1[cl];
  const float Lres = p0[8 + cl] + p1[8 + cl];   // cols 8..23 = res logits 0..15
  const float ssqt = ssqP[(size_t)(tile * 2) * 16 + tok] + ssqP[(size_t)(tile * 2 + 1) * 16 + tok];
  const float invr = rsqrtf(ssqt * (1.f / NCF) + EPS);

  float* g = gates + (size_t)(tok0 + tok) * 32;
  if (cl < 4) {
    const float zp = a_pre[aidx] * Lg * invr + b_pre[(size_t)aidx * 4 + cl];
    g[cl] = 1.f / (1.f + __expf(-zp));
  } else if (cl < 8) {
    const float zq = a_post[aidx] * Lg * invr + b_post[(size_t)aidx * 4 + (cl - 4)];
    g[cl] = 2.f / (1.f + __expf(-zq));
  }
  const float tl = a_res[aidx] * Lres * invr + b_res[(size_t)aidx * 16 + cl];
  float m = __expf(tl);
  #pragma unroll
  for (int it = 0; it < 20; ++it) {
    float rs = m;
    rs += __shfl_xor(rs, 1, 64);
    rs += __shfl_xor(rs, 2, 64);
    m *= __builtin_amdgcn_rcpf(rs);
    float cs = m;
    cs += __shfl_xor(cs, 4, 64);
    cs += __shfl_xor(cs, 8, 64);
    m *= __builtin_amdgcn_rcpf(cs);
  }
  g[8 + cl] = m;
}

// ---------------- K3: streaming output pass  [r6-proven] ----------------
__global__ __launch_bounds__(256)
void out_pass(const float* __restrict__ x, const float* __restrict__ outp,
              const float* __restrict__ gates,
              float* __restrict__ agg, float* __restrict__ big) {
  const int tok = blockIdx.x;
  const int tid = threadIdx.x;
  const float* g = gates + (size_t)tok * 32;
  float hp[4], hq[4], M[16];
  #pragma unroll
  for (int i = 0; i < 4; ++i) { hp[i] = g[i]; hq[i] = g[4 + i]; }
  #pragma unroll
  for (int i = 0; i < 16; ++i) M[i] = g[8 + i];

  const float* xrow = x + (size_t)tok * NCF;
  const float* orow = outp + (size_t)tok * CCH;
  float* arow = agg + (size_t)tok * CCH;
  float* brow = big + (size_t)tok * NCF;

  #pragma unroll
  for (int rep = 0; rep < 2; ++rep) {
    const int c = rep * 1024 + tid * 4;
    float4 xv[4];
    #pragma unroll
    for (int j = 0; j < 4; ++j) xv[j] = *(const float4*)(xrow + j * CCH + c);
    const float4 ov = *(const float4*)(orow + c);

    f32x4 ag;
    ag.x = hp[0]*xv[0].x + hp[1]*xv[1].x + hp[2]*xv[2].x + hp[3]*xv[3].x;
    ag.y = hp[0]*xv[0].y + hp[1]*xv[1].y + hp[2]*xv[2].y + hp[3]*xv[3].y;
    ag.z = hp[0]*xv[0].z + hp[1]*xv[1].z + hp[2]*xv[2].z + hp[3]*xv[3].z;
    ag.w = hp[0]*xv[0].w + hp[1]*xv[1].w + hp[2]*xv[2].w + hp[3]*xv[3].w;
    __builtin_nontemporal_store(ag, (f32x4*)(arow + c));

    #pragma unroll
    for (int i = 0; i < 4; ++i) {
      const float m0 = M[i*4+0], m1 = M[i*4+1], m2 = M[i*4+2], m3 = M[i*4+3];
      f32x4 o;
      o.x = m0*xv[0].x + m1*xv[1].x + m2*xv[2].x + m3*xv[3].x + hq[i]*ov.x;
      o.y = m0*xv[0].y + m1*xv[1].y + m2*xv[2].y + m3*xv[3].y + hq[i]*ov.y;
      o.z = m0*xv[0].z + m1*xv[1].z + m2*xv[2].z + m3*xv[3].z + hq[i]*ov.z;
      o.w = m0*xv[0].w + m1*xv[1].w + m2*xv[2].w + m3*xv[3].w + hq[i]*ov.w;
      __builtin_nontemporal_store(o, (f32x4*)(brow + i * CCH + c));
    }
  }
}

// ---------------- fallback: round-1 fused kernel (used if ws too small) ----------------
__global__ __launch_bounds__(256, 4)
void lora_fused(const float* __restrict__ x, const float* __restrict__ outp,
                const float* __restrict__ wnorm, const float* __restrict__ phi_pre,
                const float* __restrict__ phi_post, const float* __restrict__ phi_res,
                const float* __restrict__ b_pre, const float* __restrict__ b_post,
                const float* __restrict__ b_res, const float* __restrict__ a_pre,
                const float* __restrict__ a_post, const float* __restrict__ a_res,
                const int* __restrict__ aidx_arr, float* __restrict__ agg_out,
                float* __restrict__ big_out) {
  __shared__ unsigned short xsb[2][NCF];
  __shared__ float scratch[4][52];
  __shared__ float red[52];
  __shared__ float Hpre[2][4], Hpost[2][4], Msm[2][16];
  const int tid = threadIdx.x;
  const int tok0 = blockIdx.x * 2;
  const int aidx = aidx_arr[tok0 >> 10];
  const float* xr0 = x + (size_t)tok0 * NCF;
  const float* xr1 = xr0 + NCF;
  const float* wr = wnorm + (size_t)aidx * NCF;
  const float* pp = phi_pre + (size_t)aidx * NCF * 4;
  const float* pq = phi_post + (size_t)aidx * NCF * 4;
  const float* pr = phi_res + (size_t)aidx * NCF * 16;
  float acc[50];
  #pragma unroll
  for (int i = 0; i < 50; ++i) acc[i] = 0.f;
  for (int k = 0; k < 8; ++k) {
    const int f0 = (k * 256 + tid) * 4;
    const float4 w4 = *(const float4*)(wr + f0);
    const float4 xa = *(const float4*)(xr0 + f0);
    const float4 xb = *(const float4*)(xr1 + f0);
    acc[0] += xa.x*xa.x + xa.y*xa.y + xa.z*xa.z + xa.w*xa.w;
    acc[25] += xb.x*xb.x + xb.y*xb.y + xb.z*xb.z + xb.w*xb.w;
    float xw0[4] = { xa.x*w4.x, xa.y*w4.y, xa.z*w4.z, xa.w*w4.w };
    float xw1[4] = { xb.x*w4.x, xb.y*w4.y, xb.z*w4.z, xb.w*w4.w };
    *(ushort4*)&xsb[0][f0] = make_ushort4(f2bf(xa.x), f2bf(xa.y), f2bf(xa.z), f2bf(xa.w));
    *(ushort4*)&xsb[1][f0] = make_ushort4(f2bf(xb.x), f2bf(xb.y), f2bf(xb.z), f2bf(xb.w));
    #pragma unroll
    for (int d = 0; d < 4; ++d) {
      const int f = f0 + d;
      const float a0 = xw0[d], a1 = xw1[d];
      float col[24];
      const float4 P = *(const float4*)(pp + ((size_t)f << 2));
      const float4 Q = *(const float4*)(pq + ((size_t)f << 2));
      const float4 R0 = *(const float4*)(pr + ((size_t)f << 4));
      const float4 R1 = *(const float4*)(pr + ((size_t)f << 4) + 4);
      const float4 R2 = *(const float4*)(pr + ((size_t)f << 4) + 8);
      const float4 R3 = *(const float4*)(pr + ((size_t)f << 4) + 12);
      col[0]=P.x; col[1]=P.y; col[2]=P.z; col[3]=P.w;
      col[4]=Q.x; col[5]=Q.y; col[6]=Q.z; col[7]=Q.w;
      col[8]=R0.x; col[9]=R0.y; col[10]=R0.z; col[11]=R0.w;
      col[12]=R1.x; col[13]=R1.y; col[14]=R1.z; col[15]=R1.w;
      col[16]=R2.x; col[17]=R2.y; col[18]=R2.z; col[19]=R2.w;
      col[20]=R3.x; col[21]=R3.y; col[22]=R3.z; col[23]=R3.w;
      #pragma unroll
      for (int c = 0; c < 24; ++c) { acc[1 + c] += a0 * col[c]; acc[26 + c] += a1 * col[c]; }
    }
  }
  #pragma unroll
  for (int m = 1; m <= 32; m <<= 1) {
    #pragma unroll
    for (int v = 0; v < 50; ++v) acc[v] += __shfl_xor(acc[v], m, 64);
  }
  const int wave = tid >> 6, lane = tid & 63;
  if (lane == 0) {
    #pragma unroll
    for (int v = 0; v < 50; ++v) scratch[wave][v] = acc[v];
  }
  __syncthreads();
  if (tid < 50) red[tid] = scratch[0][tid] + scratch[1][tid] + scratch[2][tid] + scratch[3][tid];
  __syncthreads();
  if (tid < 32) {
    const int t = tid >> 4, l = tid & 15;
    const float invr = rsqrtf(red[t * 25] * (1.f / NCF) + EPS);
    const float tl = a_res[aidx] * red[t * 25 + 1 + 8 + l] * invr + b_res[(size_t)aidx * 16 + l];
    float m = __expf(tl);
    #pragma unroll
    for (int it = 0; it < 20; ++it) {
      float rs = m; rs += __shfl_xor(rs, 1, 64); rs += __shfl_xor(rs, 2, 64);
      m *= __builtin_amdgcn_rcpf(rs);
      float cs = m; cs += __shfl_xor(cs, 4, 64); cs += __shfl_xor(cs, 8, 64);
      m *= __builtin_amdgcn_rcpf(cs);
    }
    Msm[t][l] = m;
  } else if (tid < 40) {
    const int q = tid - 32, t = q >> 2, n = q & 3;
    const float invr = rsqrtf(red[t * 25] * (1.f / NCF) + EPS);
    const float zp = a_pre[aidx] * red[t * 25 + 1 + n] * invr + b_pre[(size_t)aidx * 4 + n];
    const float zq = a_post[aidx] * red[t * 25 + 1 + 4 + n] * invr + b_post[(size_t)aidx * 4 + n];
    Hpre[t][n] = 1.f / (1.f + __expf(-zp));
    Hpost[t][n] = 2.f / (1.f + __expf(-zq));
  }
  __syncthreads();
  #pragma unroll
  for (int t = 0; t < 2; ++t) {
    const int tok = tok0 + t;
    const float* orow = outp + (size_t)tok * CCH;
    float* arow = agg_out + (size_t)tok * CCH;
    float* brow = big_out + (size_t)tok * 4 * CCH;
    const float hp0 = Hpre[t][0], hp1 = Hpre[t][1], hp2 = Hpre[t][2], hp3 = Hpre[t][3];
    float Mr[16];
    #pragma unroll
    for (int i = 0; i < 16; ++i) Mr[i] = Msm[t][i];
    const float hq[4] = { Hpost[t][0], Hpost[t][1], Hpost[t][2], Hpost[t][3] };
    #pragma unroll
    for (int w = 0; w < 2; ++w) {
      const int c0 = (w * 256 + tid) * 4;
      float4 xv[4];
      #pragma unroll
      for (int n = 0; n < 4; ++n) {
        const ushort4 u = *(const ushort4*)&xsb[t][n * CCH + c0];
        xv[n] = make_float4(bf2f(u.x), bf2f(u.y), bf2f(u.z), bf2f(u.w));
      }
      const float4 ov = *(const float4*)(orow + c0);
      float4 ag;
      ag.x = hp0*xv[0].x + hp1*xv[1].x + hp2*xv[2].x + hp3*xv[3].x;
      ag.y = hp0*xv[0].y + hp1*xv[1].y + hp2*xv[2].y + hp3*xv[3].y;
      ag.z = hp0*xv[0].z + hp1*xv[1].z + hp2*xv[2].z + hp3*xv[3].z;
      ag.w = hp0*xv[0].w + hp1*xv[1].w + hp2*xv[2].w + hp3*xv[3].w;
      *(float4*)(arow + c0) = ag;
      #pragma unroll
      for (int i = 0; i < 4; ++i) {
        const float m0 = Mr[i*4+0], m1 = Mr[i*4+1], m2 = Mr[i*4+2], m3 = Mr[i*4+3];
        float4 o;
        o.x = m0*xv[0].x + m1*xv[1].x + m2*xv[2].x + m3*xv[3].x + hq[i]*ov.x;
        o.y = m0*xv[0].y + m1*xv[1].y + m2*xv[2].y + m3*xv[3].y + hq[i]*ov.y;
        o.z = m0*xv[0].z + m1*xv[1].z + m2*xv[2].z + m3*xv[3].z + hq[i]*ov.z;
        o.w = m0*xv[0].w + m1*xv[1].w + m2*xv[2].w + m3*xv[3].w + hq[i]*ov.w;
        *(float4*)(brow + (size_t)i * CCH + c0) = o;
      }
    }
  }
}

extern "C" void kernel_launch(void* const* d_in, const int* in_sizes, int n_in,
                              void* d_out, int out_size, void* d_ws, size_t ws_size,
                              hipStream_t stream) {
  const float* x     = (const float*)d_in[0];
  const float* outp  = (const float*)d_in[1];
  const float* wnorm = (const float*)d_in[2];
  const float* ppre  = (const float*)d_in[3];
  const float* ppost = (const float*)d_in[4];
  const float* pres  = (const float*)d_in[5];
  const float* bpre  = (const float*)d_in[6];
  const float* bpost = (const float*)d_in[7];
  const float* bres  = (const float*)d_in[8];
  const float* apre  = (const float*)d_in[9];
  const float* apost = (const float*)d_in[10];
  const float* ares  = (const float*)d_in[11];
  const int*   aidx  = (const int*)d_in[12];

  float* agg = (float*)d_out;
  float* big = (float*)d_out + (size_t)TOKS * CCH;

  if (ws_size >= WS_NEED) {
    unsigned short* phiT = (unsigned short*)d_ws;
    float* logP  = (float*)((char*)d_ws + LOGP_OFF);
    float* ssqP  = (float*)((char*)d_ws + SSQP_OFF);
    float* gates = (float*)((char*)d_ws + GATES_OFF);
    hipLaunchKernelGGL(prep_phiT, dim3(1024), dim3(256), 0, stream,
                       ppre, ppost, pres, wnorm, phiT);
    hipLaunchKernelGGL(logits_partial, dim3(512), dim3(512), 0, stream,
                       x, phiT, aidx, logP, ssqP);
    hipLaunchKernelGGL(gates_kernel, dim3(256), dim3(256), 0, stream,
                       logP, ssqP, bpre, bpost, bres, apre, apost, ares, aidx, gates);
    hipLaunchKernelGGL(out_pass, dim3(4096), dim3(256), 0, stream, x, outp, gates, agg, big);
  } else {
    hipLaunchKernelGGL(lora_fused, dim3(2048), dim3(256), 0, stream,
                       x, outp, wnorm, ppre, ppost, pres,
                       bpre, bpost, bres, apre, apost, ares, aidx, agg, big);
  }
}

// Round 12
// 110.452 us; speedup vs baseline: 1.4453x; 1.3560x over previous
//
#include <hip/hip_runtime.h>

#define EPS 1e-5f
#define TOKS 4096
#define NCF 8192
#define CCH 2048

#define PHI_BYTES ((size_t)8 * 32 * 8192 * 2)            // 4 MB bf16 phiT'
#define GATES_OFF PHI_BYTES                              // float[4096][32] = 512 KB
#define WS_NEED   (GATES_OFF + (size_t)TOKS * 32 * 4)

typedef __attribute__((ext_vector_type(8))) short bf16x8;
typedef __attribute__((ext_vector_type(4))) float f32x4;

__device__ __forceinline__ unsigned short f2bf(float f) {
  unsigned int u = __float_as_uint(f);
  u += 0x7FFFu + ((u >> 16) & 1u);
  return (unsigned short)(u >> 16);
}
__device__ __forceinline__ float bf2f(unsigned short s) {
  return __uint_as_float(((unsigned int)s) << 16);
}

// ---------------- K0: phiT'[a][r][f] = w[a][f] * phi_r[a][f]  (bf16, [A][32][8192]) ----------------
// rows 0-3 = pre cols, 4-7 = post cols, 8-23 = res cols, 24-31 = zero   [r10/r11-proven]
__global__ __launch_bounds__(256)
void prep_phiT(const float* __restrict__ pre, const float* __restrict__ post,
               const float* __restrict__ res, const float* __restrict__ wnorm,
               unsigned short* __restrict__ phiT) {
  const int gid = blockIdx.x * 256 + threadIdx.x;   // 8*32*1024
  const int a = gid >> 15;
  const int r = (gid >> 10) & 31;
  const int f = (gid & 1023) * 8;
  const float4 wA = *(const float4*)(wnorm + (size_t)a * NCF + f);
  const float4 wB = *(const float4*)(wnorm + (size_t)a * NCF + f + 4);
  const float wv[8] = { wA.x, wA.y, wA.z, wA.w, wB.x, wB.y, wB.z, wB.w };
  unsigned int w[4];
  #pragma unroll
  for (int p = 0; p < 4; ++p) {
    float v0 = 0.f, v1 = 0.f;
    const int e0 = f + 2 * p, e1 = f + 2 * p + 1;
    if (r < 4) {
      v0 = pre[((size_t)a * NCF + e0) * 4 + r];
      v1 = pre[((size_t)a * NCF + e1) * 4 + r];
    } else if (r < 8) {
      v0 = post[((size_t)a * NCF + e0) * 4 + (r - 4)];
      v1 = post[((size_t)a * NCF + e1) * 4 + (r - 4)];
    } else if (r < 24) {
      v0 = res[((size_t)a * NCF + e0) * 16 + (r - 8)];
      v1 = res[((size_t)a * NCF + e1) * 16 + (r - 8)];
    }
    v0 *= wv[2 * p];
    v1 *= wv[2 * p + 1];
    w[p] = (unsigned int)f2bf(v0) | ((unsigned int)f2bf(v1) << 16);
  }
  *(uint4*)(phiT + ((size_t)a * 32 + r) * NCF + f) = make_uint4(w[0], w[1], w[2], w[3]);
}

// ---------------- K1: r6 skeleton + w-folded phiT + depth-2 load pipeline ----------------
// grid 256, 512 threads = 8 waves; wave w owns K-slice [w*1024,(w+1)*1024), 4 chunks of 256.
// xa/xb hold chunks t and t+1; prefetch t+2 into consumed buffer during staging.
__global__ __launch_bounds__(512, 2)
void logits_gates(const float* __restrict__ x,
                  const unsigned short* __restrict__ phiT,
                  const float* __restrict__ b_pre, const float* __restrict__ b_post,
                  const float* __restrict__ b_res,
                  const float* __restrict__ a_pre, const float* __restrict__ a_post,
                  const float* __restrict__ a_res,
                  const int* __restrict__ aidx_arr,
                  float* __restrict__ gates) {
  __shared__ unsigned short xs[8][16 * 264];   // per-wave bf16 tile [16 tok][256], pad 264
  __shared__ float logits_s[8][16][32];
  __shared__ float ssq_s[8][16];

  const int tid = threadIdx.x;
  const int wave = tid >> 6, lane = tid & 63;
  const int tok0 = blockIdx.x * 16;
  const int aidx = aidx_arr[tok0 >> 10];
  const int kbase = wave * 1024;

  const float* xbase = x + (size_t)tok0 * NCF + kbase + lane * 4;
  const unsigned short* pBbase =
      phiT + ((size_t)aidx * 32 + (lane & 15)) * NCF + kbase + (lane >> 4) * 8;

  f32x4 acc0 = {0.f, 0.f, 0.f, 0.f};
  f32x4 acc1 = {0.f, 0.f, 0.f, 0.f};
  float ssq[16];
  #pragma unroll
  for (int r = 0; r < 16; ++r) ssq[r] = 0.f;

  float4 xa[16], xb[16];
  #pragma unroll
  for (int r = 0; r < 16; ++r) xa[r] = *(const float4*)(xbase + (size_t)r * NCF);
  #pragma unroll
  for (int r = 0; r < 16; ++r) xb[r] = *(const float4*)(xbase + (size_t)r * NCF + 256);

  #pragma unroll
  for (int t = 0; t < 4; ++t) {
    // stage current chunk (xa if t even, xb if t odd); prefetch chunk t+2 into it
    #pragma unroll
    for (int r = 0; r < 16; ++r) {
      const float4 v = (t & 1) ? xb[r] : xa[r];
      ssq[r] += v.x * v.x + v.y * v.y + v.z * v.z + v.w * v.w;
      *(ushort4*)&xs[wave][r * 264 + lane * 4] =
          make_ushort4(f2bf(v.x), f2bf(v.y), f2bf(v.z), f2bf(v.w));
      if (t < 2) {
        const float4 nv = *(const float4*)(xbase + (size_t)r * NCF + (t + 2) * 256);
        if (t & 1) xb[r] = nv; else xa[r] = nv;
      }
    }
    const unsigned short* pB = pBbase + t * 256;
    #pragma unroll
    for (int s = 0; s < 8; ++s) {
      bf16x8 a = *(const bf16x8*)&xs[wave][(lane & 15) * 264 + s * 32 + (lane >> 4) * 8];
      bf16x8 b0 = *(const bf16x8*)(pB + s * 32);
      bf16x8 b1 = *(const bf16x8*)(pB + 16 * NCF + s * 32);
      acc0 = __builtin_amdgcn_mfma_f32_16x16x32_bf16(a, b0, acc0, 0, 0, 0);
      acc1 = __builtin_amdgcn_mfma_f32_16x16x32_bf16(a, b1, acc1, 0, 0, 0);
    }
  }

  // ssq reduce across 64 lanes
  #pragma unroll
  for (int r = 0; r < 16; ++r) {
    float v = ssq[r];
    #pragma unroll
    for (int m = 1; m <= 32; m <<= 1) v += __shfl_xor(v, m, 64);
    if (lane == 0) ssq_s[wave][r] = v;
  }
  // C frags -> LDS: D[m=tok][n=col], col=lane&15, row=(lane>>4)*4+i  [r6-proven]
  #pragma unroll
  for (int i = 0; i < 4; ++i) {
    logits_s[wave][(lane >> 4) * 4 + i][lane & 15] = acc0[i];
    logits_s[wave][(lane >> 4) * 4 + i][16 + (lane & 15)] = acc1[i];
  }
  __syncthreads();

  if (tid < 256) {
    // per-thread: tok = tid>>4 (0..15), cl = tid&15   [r6-proven verbatim]
    const int tok = tid >> 4, cl = tid & 15;
    float L0 = 0.f, L16 = 0.f, ssqt = 0.f;
    #pragma unroll
    for (int w = 0; w < 8; ++w) {
      L0 += logits_s[w][tok][cl];
      L16 += logits_s[w][tok][16 + cl];
      ssqt += ssq_s[w][tok];
    }
    const float invr = rsqrtf(ssqt * (1.f / NCF) + EPS);

    float* g = gates + (size_t)(tok0 + tok) * 32;
    if (cl < 4) {
      const float zp = a_pre[aidx] * L0 * invr + b_pre[(size_t)aidx * 4 + cl];
      g[cl] = 1.f / (1.f + __expf(-zp));
    } else if (cl < 8) {
      const float zq = a_post[aidx] * L0 * invr + b_post[(size_t)aidx * 4 + (cl - 4)];
      g[cl] = 2.f / (1.f + __expf(-zq));
    }
    // gather res logits: res[cl] = col 8+cl
    const float resv = __shfl_xor((cl & 8) ? L0 : L16, 8, 64);
    const float tl = a_res[aidx] * resv * invr + b_res[(size_t)aidx * 16 + cl];
    float m = __expf(tl);
    #pragma unroll
    for (int it = 0; it < 20; ++it) {
      float rs = m;
      rs += __shfl_xor(rs, 1, 64);
      rs += __shfl_xor(rs, 2, 64);
      m *= __builtin_amdgcn_rcpf(rs);
      float cs = m;
      cs += __shfl_xor(cs, 4, 64);
      cs += __shfl_xor(cs, 8, 64);
      m *= __builtin_amdgcn_rcpf(cs);
    }
    g[8 + cl] = m;
  }
}

// ---------------- K3: streaming output pass  [r6-proven] ----------------
__global__ __launch_bounds__(256)
void out_pass(const float* __restrict__ x, const float* __restrict__ outp,
              const float* __restrict__ gates,
              float* __restrict__ agg, float* __restrict__ big) {
  const int tok = blockIdx.x;
  const int tid = threadIdx.x;
  const float* g = gates + (size_t)tok * 32;
  float hp[4], hq[4], M[16];
  #pragma unroll
  for (int i = 0; i < 4; ++i) { hp[i] = g[i]; hq[i] = g[4 + i]; }
  #pragma unroll
  for (int i = 0; i < 16; ++i) M[i] = g[8 + i];

  const float* xrow = x + (size_t)tok * NCF;
  const float* orow = outp + (size_t)tok * CCH;
  float* arow = agg + (size_t)tok * CCH;
  float* brow = big + (size_t)tok * NCF;

  #pragma unroll
  for (int rep = 0; rep < 2; ++rep) {
    const int c = rep * 1024 + tid * 4;
    float4 xv[4];
    #pragma unroll
    for (int j = 0; j < 4; ++j) xv[j] = *(const float4*)(xrow + j * CCH + c);
    const float4 ov = *(const float4*)(orow + c);

    f32x4 ag;
    ag.x = hp[0]*xv[0].x + hp[1]*xv[1].x + hp[2]*xv[2].x + hp[3]*xv[3].x;
    ag.y = hp[0]*xv[0].y + hp[1]*xv[1].y + hp[2]*xv[2].y + hp[3]*xv[3].y;
    ag.z = hp[0]*xv[0].z + hp[1]*xv[1].z + hp[2]*xv[2].z + hp[3]*xv[3].z;
    ag.w = hp[0]*xv[0].w + hp[1]*xv[1].w + hp[2]*xv[2].w + hp[3]*xv[3].w;
    __builtin_nontemporal_store(ag, (f32x4*)(arow + c));

    #pragma unroll
    for (int i = 0; i < 4; ++i) {
      const float m0 = M[i*4+0], m1 = M[i*4+1], m2 = M[i*4+2], m3 = M[i*4+3];
      f32x4 o;
      o.x = m0*xv[0].x + m1*xv[1].x + m2*xv[2].x + m3*xv[3].x + hq[i]*ov.x;
      o.y = m0*xv[0].y + m1*xv[1].y + m2*xv[2].y + m3*xv[3].y + hq[i]*ov.y;
      o.z = m0*xv[0].z + m1*xv[1].z + m2*xv[2].z + m3*xv[3].z + hq[i]*ov.z;
      o.w = m0*xv[0].w + m1*xv[1].w + m2*xv[2].w + m3*xv[3].w + hq[i]*ov.w;
      __builtin_nontemporal_store(o, (f32x4*)(brow + i * CCH + c));
    }
  }
}

// ---------------- fallback: round-1 fused kernel (used if ws too small) ----------------
__global__ __launch_bounds__(256, 4)
void lora_fused(const float* __restrict__ x, const float* __restrict__ outp,
                const float* __restrict__ wnorm, const float* __restrict__ phi_pre,
                const float* __restrict__ phi_post, const float* __restrict__ phi_res,
                const float* __restrict__ b_pre, const float* __restrict__ b_post,
                const float* __restrict__ b_res, const float* __restrict__ a_pre,
                const float* __restrict__ a_post, const float* __restrict__ a_res,
                const int* __restrict__ aidx_arr, float* __restrict__ agg_out,
                float* __restrict__ big_out) {
  __shared__ unsigned short xsb[2][NCF];
  __shared__ float scratch[4][52];
  __shared__ float red[52];
  __shared__ float Hpre[2][4], Hpost[2][4], Msm[2][16];
  const int tid = threadIdx.x;
  const int tok0 = blockIdx.x * 2;
  const int aidx = aidx_arr[tok0 >> 10];
  const float* xr0 = x + (size_t)tok0 * NCF;
  const float* xr1 = xr0 + NCF;
  const float* wr = wnorm + (size_t)aidx * NCF;
  const float* pp = phi_pre + (size_t)aidx * NCF * 4;
  const float* pq = phi_post + (size_t)aidx * NCF * 4;
  const float* pr = phi_res + (size_t)aidx * NCF * 16;
  float acc[50];
  #pragma unroll
  for (int i = 0; i < 50; ++i) acc[i] = 0.f;
  for (int k = 0; k < 8; ++k) {
    const int f0 = (k * 256 + tid) * 4;
    const float4 w4 = *(const float4*)(wr + f0);
    const float4 xa = *(const float4*)(xr0 + f0);
    const float4 xb = *(const float4*)(xr1 + f0);
    acc[0] += xa.x*xa.x + xa.y*xa.y + xa.z*xa.z + xa.w*xa.w;
    acc[25] += xb.x*xb.x + xb.y*xb.y + xb.z*xb.z + xb.w*xb.w;
    float xw0[4] = { xa.x*w4.x, xa.y*w4.y, xa.z*w4.z, xa.w*w4.w };
    float xw1[4] = { xb.x*w4.x, xb.y*w4.y, xb.z*w4.z, xb.w*w4.w };
    *(ushort4*)&xsb[0][f0] = make_ushort4(f2bf(xa.x), f2bf(xa.y), f2bf(xa.z), f2bf(xa.w));
    *(ushort4*)&xsb[1][f0] = make_ushort4(f2bf(xb.x), f2bf(xb.y), f2bf(xb.z), f2bf(xb.w));
    #pragma unroll
    for (int d = 0; d < 4; ++d) {
      const int f = f0 + d;
      const float a0 = xw0[d], a1 = xw1[d];
      float col[24];
      const float4 P = *(const float4*)(pp + ((size_t)f << 2));
      const float4 Q = *(const float4*)(pq + ((size_t)f << 2));
      const float4 R0 = *(const float4*)(pr + ((size_t)f << 4));
      const float4 R1 = *(const float4*)(pr + ((size_t)f << 4) + 4);
      const float4 R2 = *(const float4*)(pr + ((size_t)f << 4) + 8);
      const float4 R3 = *(const float4*)(pr + ((size_t)f << 4) + 12);
      col[0]=P.x; col[1]=P.y; col[2]=P.z; col[3]=P.w;
      col[4]=Q.x; col[5]=Q.y; col[6]=Q.z; col[7]=Q.w;
      col[8]=R0.x; col[9]=R0.y; col[10]=R0.z; col[11]=R0.w;
      col[12]=R1.x; col[13]=R1.y; col[14]=R1.z; col[15]=R1.w;
      col[16]=R2.x; col[17]=R2.y; col[18]=R2.z; col[19]=R2.w;
      col[20]=R3.x; col[21]=R3.y; col[22]=R3.z; col[23]=R3.w;
      #pragma unroll
      for (int c = 0; c < 24; ++c) { acc[1 + c] += a0 * col[c]; acc[26 + c] += a1 * col[c]; }
    }
  }
  #pragma unroll
  for (int m = 1; m <= 32; m <<= 1) {
    #pragma unroll
    for (int v = 0; v < 50; ++v) acc[v] += __shfl_xor(acc[v], m, 64);
  }
  const int wave = tid >> 6, lane = tid & 63;
  if (lane == 0) {
    #pragma unroll
    for (int v = 0; v < 50; ++v) scratch[wave][v] = acc[v];
  }
  __syncthreads();
  if (tid < 50) red[tid] = scratch[0][tid] + scratch[1][tid] + scratch[2][tid] + scratch[3][tid];
  __syncthreads();
  if (tid < 32) {
    const int t = tid >> 4, l = tid & 15;
    const float invr = rsqrtf(red[t * 25] * (1.f / NCF) + EPS);
    const float tl = a_res[aidx] * red[t * 25 + 1 + 8 + l] * invr + b_res[(size_t)aidx * 16 + l];
    float m = __expf(tl);
    #pragma unroll
    for (int it = 0; it < 20; ++it) {
      float rs = m; rs += __shfl_xor(rs, 1, 64); rs += __shfl_xor(rs, 2, 64);
      m *= __builtin_amdgcn_rcpf(rs);
      float cs = m; cs += __shfl_xor(cs, 4, 64); cs += __shfl_xor(cs, 8, 64);
      m *= __builtin_amdgcn_rcpf(cs);
    }
    Msm[t][l] = m;
  } else if (tid < 40) {
    const int q = tid - 32, t = q >> 2, n = q & 3;
    const float invr = rsqrtf(red[t * 25] * (1.f / NCF) + EPS);
    const float zp = a_pre[aidx] * red[t * 25 + 1 + n] * invr + b_pre[(size_t)aidx * 4 + n];
    const float zq = a_post[aidx] * red[t * 25 + 1 + 4 + n] * invr + b_post[(size_t)aidx * 4 + n];
    Hpre[t][n] = 1.f / (1.f + __expf(-zp));
    Hpost[t][n] = 2.f / (1.f + __expf(-zq));
  }
  __syncthreads();
  #pragma unroll
  for (int t = 0; t < 2; ++t) {
    const int tok = tok0 + t;
    const float* orow = outp + (size_t)tok * CCH;
    float* arow = agg_out + (size_t)tok * CCH;
    float* brow = big_out + (size_t)tok * 4 * CCH;
    const float hp0 = Hpre[t][0], hp1 = Hpre[t][1], hp2 = Hpre[t][2], hp3 = Hpre[t][3];
    float Mr[16];
    #pragma unroll
    for (int i = 0; i < 16; ++i) Mr[i] = Msm[t][i];
    const float hq[4] = { Hpost[t][0], Hpost[t][1], Hpost[t][2], Hpost[t][3] };
    #pragma unroll
    for (int w = 0; w < 2; ++w) {
      const int c0 = (w * 256 + tid) * 4;
      float4 xv[4];
      #pragma unroll
      for (int n = 0; n < 4; ++n) {
        const ushort4 u = *(const ushort4*)&xsb[t][n * CCH + c0];
        xv[n] = make_float4(bf2f(u.x), bf2f(u.y), bf2f(u.z), bf2f(u.w));
      }
      const float4 ov = *(const float4*)(orow + c0);
      float4 ag;
      ag.x = hp0*xv[0].x + hp1*xv[1].x + hp2*xv[2].x + hp3*xv[3].x;
      ag.y = hp0*xv[0].y + hp1*xv[1].y + hp2*xv[2].y + hp3*xv[3].y;
      ag.z = hp0*xv[0].z + hp1*xv[1].z + hp2*xv[2].z + hp3*xv[3].z;
      ag.w = hp0*xv[0].w + hp1*xv[1].w + hp2*xv[2].w + hp3*xv[3].w;
      *(float4*)(arow + c0) = ag;
      #pragma unroll
      for (int i = 0; i < 4; ++i) {
        const float m0 = Mr[i*4+0], m1 = Mr[i*4+1], m2 = Mr[i*4+2], m3 = Mr[i*4+3];
        float4 o;
        o.x = m0*xv[0].x + m1*xv[1].x + m2*xv[2].x + m3*xv[3].x + hq[i]*ov.x;
        o.y = m0*xv[0].y + m1*xv[1].y + m2*xv[2].y + m3*xv[3].y + hq[i]*ov.y;
        o.z = m0*xv[0].z + m1*xv[1].z + m2*xv[2].z + m3*xv[3].z + hq[i]*ov.z;
        o.w = m0*xv[0].w + m1*xv[1].w + m2*xv[2].w + m3*xv[3].w + hq[i]*ov.w;
        *(float4*)(brow + (size_t)i * CCH + c0) = o;
      }
    }
  }
}

extern "C" void kernel_launch(void* const* d_in, const int* in_sizes, int n_in,
                              void* d_out, int out_size, void* d_ws, size_t ws_size,
                              hipStream_t stream) {
  const float* x     = (const float*)d_in[0];
  const float* outp  = (const float*)d_in[1];
  const float* wnorm = (const float*)d_in[2];
  const float* ppre  = (const float*)d_in[3];
  const float* ppost = (const float*)d_in[4];
  const float* pres  = (const float*)d_in[5];
  const float* bpre  = (const float*)d_in[6];
  const float* bpost = (const float*)d_in[7];
  const float* bres  = (const float*)d_in[8];
  const float* apre  = (const float*)d_in[9];
  const float* apost = (const float*)d_in[10];
  const float* ares  = (const float*)d_in[11];
  const int*   aidx  = (const int*)d_in[12];

  float* agg = (float*)d_out;
  float* big = (float*)d_out + (size_t)TOKS * CCH;

  if (ws_size >= WS_NEED) {
    unsigned short* phiT = (unsigned short*)d_ws;
    float* gates = (float*)((char*)d_ws + GATES_OFF);
    hipLaunchKernelGGL(prep_phiT, dim3(1024), dim3(256), 0, stream,
                       ppre, ppost, pres, wnorm, phiT);
    hipLaunchKernelGGL(logits_gates, dim3(256), dim3(512), 0, stream,
                       x, phiT, bpre, bpost, bres, apre, apost, ares, aidx, gates);
    hipLaunchKernelGGL(out_pass, dim3(4096), dim3(256), 0, stream, x, outp, gates, agg, big);
  } else {
    hipLaunchKernelGGL(lora_fused, dim3(2048), dim3(256), 0, stream,
                       x, outp, wnorm, ppre, ppost, pres,
                       bpre, bpost, bres, apre, apost, ares, aidx, agg, big);
  }
}

// Round 13
// 109.926 us; speedup vs baseline: 1.4522x; 1.0048x over previous
//
#include <hip/hip_runtime.h>

#define EPS 1e-5f
#define TOKS 4096
#define NCF 8192
#define CCH 2048

#define PHI_BYTES ((size_t)8 * 32 * 8192 * 2)            // 4 MB bf16 phiT'
#define GATES_OFF PHI_BYTES                              // float[4096][32] = 512 KB
#define WS_NEED   (GATES_OFF + (size_t)TOKS * 32 * 4)

typedef __attribute__((ext_vector_type(8))) short bf16x8;
typedef __attribute__((ext_vector_type(4))) float f32x4;

__device__ __forceinline__ unsigned short f2bf(float f) {
  unsigned int u = __float_as_uint(f);
  u += 0x7FFFu + ((u >> 16) & 1u);
  return (unsigned short)(u >> 16);
}
__device__ __forceinline__ float bf2f(unsigned short s) {
  return __uint_as_float(((unsigned int)s) << 16);
}

__device__ __forceinline__ void gload16(const float* g, float* l) {
  __builtin_amdgcn_global_load_lds(
      (const __attribute__((address_space(1))) void*)g,
      (__attribute__((address_space(3))) void*)l, 16, 0, 0);
}

// ---------------- K0: phiT'[a][r][f] = w[a][f] * phi_r[a][f]  (bf16, [A][32][8192]) ----------------
// rows 0-3 = pre cols, 4-7 = post cols, 8-23 = res cols, 24-31 = zero   [r10/r11/r12-proven]
__global__ __launch_bounds__(256)
void prep_phiT(const float* __restrict__ pre, const float* __restrict__ post,
               const float* __restrict__ res, const float* __restrict__ wnorm,
               unsigned short* __restrict__ phiT) {
  const int gid = blockIdx.x * 256 + threadIdx.x;   // 8*32*1024
  const int a = gid >> 15;
  const int r = (gid >> 10) & 31;
  const int f = (gid & 1023) * 8;
  const float4 wA = *(const float4*)(wnorm + (size_t)a * NCF + f);
  const float4 wB = *(const float4*)(wnorm + (size_t)a * NCF + f + 4);
  const float wv[8] = { wA.x, wA.y, wA.z, wA.w, wB.x, wB.y, wB.z, wB.w };
  unsigned int w[4];
  #pragma unroll
  for (int p = 0; p < 4; ++p) {
    float v0 = 0.f, v1 = 0.f;
    const int e0 = f + 2 * p, e1 = f + 2 * p + 1;
    if (r < 4) {
      v0 = pre[((size_t)a * NCF + e0) * 4 + r];
      v1 = pre[((size_t)a * NCF + e1) * 4 + r];
    } else if (r < 8) {
      v0 = post[((size_t)a * NCF + e0) * 4 + (r - 4)];
      v1 = post[((size_t)a * NCF + e1) * 4 + (r - 4)];
    } else if (r < 24) {
      v0 = res[((size_t)a * NCF + e0) * 16 + (r - 8)];
      v1 = res[((size_t)a * NCF + e1) * 16 + (r - 8)];
    }
    v0 *= wv[2 * p];
    v1 *= wv[2 * p + 1];
    w[p] = (unsigned int)f2bf(v0) | ((unsigned int)f2bf(v1) << 16);
  }
  *(uint4*)(phiT + ((size_t)a * 32 + r) * NCF + f) = make_uint4(w[0], w[1], w[2], w[3]);
}

// ---------------- K1: async global_load_lds staging + MFMA logits + in-block gates ----------------
// grid 256 x 512 threads (8 waves). Wave w owns K-slice [w*1024,(w+1)*1024) of the 16-token tile,
// processed in 8 chunks of 128 cols, double-buffered (wave-private LDS, no barriers in K-loop).
// LDS f32 tile is XOR-swizzled on the GLOBAL SOURCE side (rule 21): 16B-block gb = lb ^ (row&7).
__global__ __launch_bounds__(512)
void logits_gates(const float* __restrict__ x,
                  const unsigned short* __restrict__ phiT,
                  const float* __restrict__ b_pre, const float* __restrict__ b_post,
                  const float* __restrict__ b_res,
                  const float* __restrict__ a_pre, const float* __restrict__ a_post,
                  const float* __restrict__ a_res,
                  const int* __restrict__ aidx_arr,
                  float* __restrict__ gates) {
  __shared__ float xsf[8][2][2048];     // 8 waves x 2 bufs x (16 rows x 128 f32) = 128 KB
  __shared__ float logAcc[16][32];
  __shared__ float ssqAcc[16];

  const int tid = threadIdx.x;
  const int wave = tid >> 6, lane = tid & 63;
  const int tok0 = blockIdx.x * 16;
  const int aidx = aidx_arr[tok0 >> 10];
  const int kbase = wave * 1024;

  // init cross-wave accumulators
  ((float*)logAcc)[tid & 511] = 0.f;    // 512 threads cover 512 slots
  if (tid < 16) ssqAcc[tid] = 0.f;
  __syncthreads();

  // staging-side per-lane constants: issue j covers rows 2j,2j+1; lane's LDS block = lane&31
  const int jr0 = lane >> 5;
  const int lb  = lane & 31;
  // read-side per-lane constants: row = lane&15, fragment block base
  const int rrow = lane & 15;
  const int lbase = ((lane >> 4) * 2) ^ (rrow & 7);   // low-3-bit value
  const int rowoff = rrow * 128;                       // floats

  const unsigned short* pBbase =
      phiT + ((size_t)aidx * 32 + rrow) * NCF + kbase + (lane >> 4) * 8;

  f32x4 acc0 = {0.f, 0.f, 0.f, 0.f};
  f32x4 acc1 = {0.f, 0.f, 0.f, 0.f};
  float ssql = 0.f;

  #define ISSUE(c, buf)                                                          \
    {                                                                            \
      float* ldsb = &xsf[wave][(buf)][0];                                        \
      _Pragma("unroll")                                                          \
      for (int j = 0; j < 8; ++j) {                                              \
        const int rr = 2 * j + jr0;                                              \
        const int gb = lb ^ (rr & 7);                                            \
        const float* gsrc =                                                      \
            x + (size_t)(tok0 + rr) * NCF + kbase + (c) * 128 + gb * 4;          \
        gload16(gsrc, ldsb + j * 256);                                           \
      }                                                                          \
    }

  ISSUE(0, 0)
  ISSUE(1, 1)

  #pragma unroll
  for (int c = 0; c < 8; ++c) {
    if (c < 7) { asm volatile("s_waitcnt vmcnt(8)" ::: "memory"); }
    else       { asm volatile("s_waitcnt vmcnt(0)" ::: "memory"); }

    const float* lbp = &xsf[wave][c & 1][0];
    const unsigned short* pB = pBbase + c * 128;
    #pragma unroll
    for (int s = 0; s < 4; ++s) {
      const int blk0 = (s * 8) | lbase;
      const float4 v0 = *(const float4*)(lbp + rowoff + blk0 * 4);
      const float4 v1 = *(const float4*)(lbp + rowoff + (blk0 ^ 1) * 4);
      ssql += v0.x*v0.x + v0.y*v0.y + v0.z*v0.z + v0.w*v0.w
            + v1.x*v1.x + v1.y*v1.y + v1.z*v1.z + v1.w*v1.w;
      bf16x8 a;
      a[0] = (short)f2bf(v0.x); a[1] = (short)f2bf(v0.y);
      a[2] = (short)f2bf(v0.z); a[3] = (short)f2bf(v0.w);
      a[4] = (short)f2bf(v1.x); a[5] = (short)f2bf(v1.y);
      a[6] = (short)f2bf(v1.z); a[7] = (short)f2bf(v1.w);
      bf16x8 b0 = *(const bf16x8*)(pB + s * 32);
      bf16x8 b1 = *(const bf16x8*)(pB + 16 * NCF + s * 32);
      acc0 = __builtin_amdgcn_mfma_f32_16x16x32_bf16(a, b0, acc0, 0, 0, 0);
      acc1 = __builtin_amdgcn_mfma_f32_16x16x32_bf16(a, b1, acc1, 0, 0, 0);
    }
    // all ds_reads of this buffer returned before we overwrite it
    asm volatile("s_waitcnt lgkmcnt(0)" ::: "memory");
    if (c < 6) ISSUE(c + 2, c & 1)
  }
  #undef ISSUE

  // ssq: lane holds partial for row rrow; reduce across the 4 quarter-lane copies
  {
    float v = ssql;
    v += __shfl_xor(v, 16, 64);
    v += __shfl_xor(v, 32, 64);
    if (lane < 16) atomicAdd(&ssqAcc[rrow], v);
  }
  // C frags: D row=(lane>>4)*4+i, col=lane&15  [r6/r11-proven mapping]
  #pragma unroll
  for (int i = 0; i < 4; ++i) {
    atomicAdd(&logAcc[(lane >> 4) * 4 + i][lane & 15], acc0[i]);
    atomicAdd(&logAcc[(lane >> 4) * 4 + i][16 + (lane & 15)], acc1[i]);
  }
  __syncthreads();

  // ---- gates: sigmoids + Sinkhorn (direct LDS reads; r11/r12-proven math) ----
  if (tid < 256) {
    const int tok = tid >> 4, cl = tid & 15;
    const float Lg   = logAcc[tok][cl];
    const float Lres = logAcc[tok][8 + cl];
    const float ssqt = ssqAcc[tok];
    const float invr = rsqrtf(ssqt * (1.f / NCF) + EPS);

    float* g = gates + (size_t)(tok0 + tok) * 32;
    if (cl < 4) {
      const float zp = a_pre[aidx] * Lg * invr + b_pre[(size_t)aidx * 4 + cl];
      g[cl] = 1.f / (1.f + __expf(-zp));
    } else if (cl < 8) {
      const float zq = a_post[aidx] * Lg * invr + b_post[(size_t)aidx * 4 + (cl - 4)];
      g[cl] = 2.f / (1.f + __expf(-zq));
    }
    const float tl = a_res[aidx] * Lres * invr + b_res[(size_t)aidx * 16 + cl];
    float m = __expf(tl);
    #pragma unroll
    for (int it = 0; it < 20; ++it) {
      float rs = m;
      rs += __shfl_xor(rs, 1, 64);
      rs += __shfl_xor(rs, 2, 64);
      m *= __builtin_amdgcn_rcpf(rs);
      float cs = m;
      cs += __shfl_xor(cs, 4, 64);
      cs += __shfl_xor(cs, 8, 64);
      m *= __builtin_amdgcn_rcpf(cs);
    }
    g[8 + cl] = m;
  }
}

// ---------------- K3: streaming output pass  [r6-proven] ----------------
__global__ __launch_bounds__(256)
void out_pass(const float* __restrict__ x, const float* __restrict__ outp,
              const float* __restrict__ gates,
              float* __restrict__ agg, float* __restrict__ big) {
  const int tok = blockIdx.x;
  const int tid = threadIdx.x;
  const float* g = gates + (size_t)tok * 32;
  float hp[4], hq[4], M[16];
  #pragma unroll
  for (int i = 0; i < 4; ++i) { hp[i] = g[i]; hq[i] = g[4 + i]; }
  #pragma unroll
  for (int i = 0; i < 16; ++i) M[i] = g[8 + i];

  const float* xrow = x + (size_t)tok * NCF;
  const float* orow = outp + (size_t)tok * CCH;
  float* arow = agg + (size_t)tok * CCH;
  float* brow = big + (size_t)tok * NCF;

  #pragma unroll
  for (int rep = 0; rep < 2; ++rep) {
    const int c = rep * 1024 + tid * 4;
    float4 xv[4];
    #pragma unroll
    for (int j = 0; j < 4; ++j) xv[j] = *(const float4*)(xrow + j * CCH + c);
    const float4 ov = *(const float4*)(orow + c);

    f32x4 ag;
    ag.x = hp[0]*xv[0].x + hp[1]*xv[1].x + hp[2]*xv[2].x + hp[3]*xv[3].x;
    ag.y = hp[0]*xv[0].y + hp[1]*xv[1].y + hp[2]*xv[2].y + hp[3]*xv[3].y;
    ag.z = hp[0]*xv[0].z + hp[1]*xv[1].z + hp[2]*xv[2].z + hp[3]*xv[3].z;
    ag.w = hp[0]*xv[0].w + hp[1]*xv[1].w + hp[2]*xv[2].w + hp[3]*xv[3].w;
    __builtin_nontemporal_store(ag, (f32x4*)(arow + c));

    #pragma unroll
    for (int i = 0; i < 4; ++i) {
      const float m0 = M[i*4+0], m1 = M[i*4+1], m2 = M[i*4+2], m3 = M[i*4+3];
      f32x4 o;
      o.x = m0*xv[0].x + m1*xv[1].x + m2*xv[2].x + m3*xv[3].x + hq[i]*ov.x;
      o.y = m0*xv[0].y + m1*xv[1].y + m2*xv[2].y + m3*xv[3].y + hq[i]*ov.y;
      o.z = m0*xv[0].z + m1*xv[1].z + m2*xv[2].z + m3*xv[3].z + hq[i]*ov.z;
      o.w = m0*xv[0].w + m1*xv[1].w + m2*xv[2].w + m3*xv[3].w + hq[i]*ov.w;
      __builtin_nontemporal_store(o, (f32x4*)(brow + i * CCH + c));
    }
  }
}

// ---------------- fallback: round-1 fused kernel (used if ws too small) ----------------
__global__ __launch_bounds__(256, 4)
void lora_fused(const float* __restrict__ x, const float* __restrict__ outp,
                const float* __restrict__ wnorm, const float* __restrict__ phi_pre,
                const float* __restrict__ phi_post, const float* __restrict__ phi_res,
                const float* __restrict__ b_pre, const float* __restrict__ b_post,
                const float* __restrict__ b_res, const float* __restrict__ a_pre,
                const float* __restrict__ a_post, const float* __restrict__ a_res,
                const int* __restrict__ aidx_arr, float* __restrict__ agg_out,
                float* __restrict__ big_out) {
  __shared__ unsigned short xsb[2][NCF];
  __shared__ float scratch[4][52];
  __shared__ float red[52];
  __shared__ float Hpre[2][4], Hpost[2][4], Msm[2][16];
  const int tid = threadIdx.x;
  const int tok0 = blockIdx.x * 2;
  const int aidx = aidx_arr[tok0 >> 10];
  const float* xr0 = x + (size_t)tok0 * NCF;
  const float* xr1 = xr0 + NCF;
  const float* wr = wnorm + (size_t)aidx * NCF;
  const float* pp = phi_pre + (size_t)aidx * NCF * 4;
  const float* pq = phi_post + (size_t)aidx * NCF * 4;
  const float* pr = phi_res + (size_t)aidx * NCF * 16;
  float acc[50];
  #pragma unroll
  for (int i = 0; i < 50; ++i) acc[i] = 0.f;
  for (int k = 0; k < 8; ++k) {
    const int f0 = (k * 256 + tid) * 4;
    const float4 w4 = *(const float4*)(wr + f0);
    const float4 xa = *(const float4*)(xr0 + f0);
    const float4 xb = *(const float4*)(xr1 + f0);
    acc[0] += xa.x*xa.x + xa.y*xa.y + xa.z*xa.z + xa.w*xa.w;
    acc[25] += xb.x*xb.x + xb.y*xb.y + xb.z*xb.z + xb.w*xb.w;
    float xw0[4] = { xa.x*w4.x, xa.y*w4.y, xa.z*w4.z, xa.w*w4.w };
    float xw1[4] = { xb.x*w4.x, xb.y*w4.y, xb.z*w4.z, xb.w*w4.w };
    *(ushort4*)&xsb[0][f0] = make_ushort4(f2bf(xa.x), f2bf(xa.y), f2bf(xa.z), f2bf(xa.w));
    *(ushort4*)&xsb[1][f0] = make_ushort4(f2bf(xb.x), f2bf(xb.y), f2bf(xb.z), f2bf(xb.w));
    #pragma unroll
    for (int d = 0; d < 4; ++d) {
      const int f = f0 + d;
      const float a0 = xw0[d], a1 = xw1[d];
      float col[24];
      const float4 P = *(const float4*)(pp + ((size_t)f << 2));
      const float4 Q = *(const float4*)(pq + ((size_t)f << 2));
      const float4 R0 = *(const float4*)(pr + ((size_t)f << 4));
      const float4 R1 = *(const float4*)(pr + ((size_t)f << 4) + 4);
      const float4 R2 = *(const float4*)(pr + ((size_t)f << 4) + 8);
      const float4 R3 = *(const float4*)(pr + ((size_t)f << 4) + 12);
      col[0]=P.x; col[1]=P.y; col[2]=P.z; col[3]=P.w;
      col[4]=Q.x; col[5]=Q.y; col[6]=Q.z; col[7]=Q.w;
      col[8]=R0.x; col[9]=R0.y; col[10]=R0.z; col[11]=R0.w;
      col[12]=R1.x; col[13]=R1.y; col[14]=R1.z; col[15]=R1.w;
      col[16]=R2.x; col[17]=R2.y; col[18]=R2.z; col[19]=R2.w;
      col[20]=R3.x; col[21]=R3.y; col[22]=R3.z; col[23]=R3.w;
      #pragma unroll
      for (int c = 0; c < 24; ++c) { acc[1 + c] += a0 * col[c]; acc[26 + c] += a1 * col[c]; }
    }
  }
  #pragma unroll
  for (int m = 1; m <= 32; m <<= 1) {
    #pragma unroll
    for (int v = 0; v < 50; ++v) acc[v] += __shfl_xor(acc[v], m, 64);
  }
  const int wave = tid >> 6, lane = tid & 63;
  if (lane == 0) {
    #pragma unroll
    for (int v = 0; v < 50; ++v) scratch[wave][v] = acc[v];
  }
  __syncthreads();
  if (tid < 50) red[tid] = scratch[0][tid] + scratch[1][tid] + scratch[2][tid] + scratch[3][tid];
  __syncthreads();
  if (tid < 32) {
    const int t = tid >> 4, l = tid & 15;
    const float invr = rsqrtf(red[t * 25] * (1.f / NCF) + EPS);
    const float tl = a_res[aidx] * red[t * 25 + 1 + 8 + l] * invr + b_res[(size_t)aidx * 16 + l];
    float m = __expf(tl);
    #pragma unroll
    for (int it = 0; it < 20; ++it) {
      float rs = m; rs += __shfl_xor(rs, 1, 64); rs += __shfl_xor(rs, 2, 64);
      m *= __builtin_amdgcn_rcpf(rs);
      float cs = m; cs += __shfl_xor(cs, 4, 64); cs += __shfl_xor(cs, 8, 64);
      m *= __builtin_amdgcn_rcpf(cs);
    }
    Msm[t][l] = m;
  } else if (tid < 40) {
    const int q = tid - 32, t = q >> 2, n = q & 3;
    const float invr = rsqrtf(red[t * 25] * (1.f / NCF) + EPS);
    const float zp = a_pre[aidx] * red[t * 25 + 1 + n] * invr + b_pre[(size_t)aidx * 4 + n];
    const float zq = a_post[aidx] * red[t * 25 + 1 + 4 + n] * invr + b_post[(size_t)aidx * 4 + n];
    Hpre[t][n] = 1.f / (1.f + __expf(-zp));
    Hpost[t][n] = 2.f / (1.f + __expf(-zq));
  }
  __syncthreads();
  #pragma unroll
  for (int t = 0; t < 2; ++t) {
    const int tok = tok0 + t;
    const float* orow = outp + (size_t)tok * CCH;
    float* arow = agg_out + (size_t)tok * CCH;
    float* brow = big_out + (size_t)tok * 4 * CCH;
    const float hp0 = Hpre[t][0], hp1 = Hpre[t][1], hp2 = Hpre[t][2], hp3 = Hpre[t][3];
    float Mr[16];
    #pragma unroll
    for (int i = 0; i < 16; ++i) Mr[i] = Msm[t][i];
    const float hq[4] = { Hpost[t][0], Hpost[t][1], Hpost[t][2], Hpost[t][3] };
    #pragma unroll
    for (int w = 0; w < 2; ++w) {
      const int c0 = (w * 256 + tid) * 4;
      float4 xv[4];
      #pragma unroll
      for (int n = 0; n < 4; ++n) {
        const ushort4 u = *(const ushort4*)&xsb[t][n * CCH + c0];
        xv[n] = make_float4(bf2f(u.x), bf2f(u.y), bf2f(u.z), bf2f(u.w));
      }
      const float4 ov = *(const float4*)(orow + c0);
      float4 ag;
      ag.x = hp0*xv[0].x + hp1*xv[1].x + hp2*xv[2].x + hp3*xv[3].x;
      ag.y = hp0*xv[0].y + hp1*xv[1].y + hp2*xv[2].y + hp3*xv[3].y;
      ag.z = hp0*xv[0].z + hp1*xv[1].z + hp2*xv[2].z + hp3*xv[3].z;
      ag.w = hp0*xv[0].w + hp1*xv[1].w + hp2*xv[2].w + hp3*xv[3].w;
      *(float4*)(arow + c0) = ag;
      #pragma unroll
      for (int i = 0; i < 4; ++i) {
        const float m0 = Mr[i*4+0], m1 = Mr[i*4+1], m2 = Mr[i*4+2], m3 = Mr[i*4+3];
        float4 o;
        o.x = m0*xv[0].x + m1*xv[1].x + m2*xv[2].x + m3*xv[3].x + hq[i]*ov.x;
        o.y = m0*xv[0].y + m1*xv[1].y + m2*xv[2].y + m3*xv[3].y + hq[i]*ov.y;
        o.z = m0*xv[0].z + m1*xv[1].z + m2*xv[2].z + m3*xv[3].z + hq[i]*ov.z;
        o.w = m0*xv[0].w + m1*xv[1].w + m2*xv[2].w + m3*xv[3].w + hq[i]*ov.w;
        *(float4*)(brow + (size_t)i * CCH + c0) = o;
      }
    }
  }
}

extern "C" void kernel_launch(void* const* d_in, const int* in_sizes, int n_in,
                              void* d_out, int out_size, void* d_ws, size_t ws_size,
                              hipStream_t stream) {
  const float* x     = (const float*)d_in[0];
  const float* outp  = (const float*)d_in[1];
  const float* wnorm = (const float*)d_in[2];
  const float* ppre  = (const float*)d_in[3];
  const float* ppost = (const float*)d_in[4];
  const float* pres  = (const float*)d_in[5];
  const float* bpre  = (const float*)d_in[6];
  const float* bpost = (const float*)d_in[7];
  const float* bres  = (const float*)d_in[8];
  const float* apre  = (const float*)d_in[9];
  const float* apost = (const float*)d_in[10];
  const float* ares  = (const float*)d_in[11];
  const int*   aidx  = (const int*)d_in[12];

  float* agg = (float*)d_out;
  float* big = (float*)d_out + (size_t)TOKS * CCH;

  if (ws_size >= WS_NEED) {
    unsigned short* phiT = (unsigned short*)d_ws;
    float* gates = (float*)((char*)d_ws + GATES_OFF);
    hipLaunchKernelGGL(prep_phiT, dim3(1024), dim3(256), 0, stream,
                       ppre, ppost, pres, wnorm, phiT);
    hipLaunchKernelGGL(logits_gates, dim3(256), dim3(512), 0, stream,
                       x, phiT, bpre, bpost, bres, apre, apost, ares, aidx, gates);
    hipLaunchKernelGGL(out_pass, dim3(4096), dim3(256), 0, stream, x, outp, gates, agg, big);
  } else {
    hipLaunchKernelGGL(lora_fused, dim3(2048), dim3(256), 0, stream,
                       x, outp, wnorm, ppre, ppost, pres,
                       bpre, bpost, bres, apre, apost, ares, aidx, agg, big);
  }
}

// Round 15
// 97.987 us; speedup vs baseline: 1.6291x; 1.1218x over previous
//
#include <hip/hip_runtime.h>

#define EPS 1e-5f
#define TOKS 4096
#define NCF 8192
#define CCH 2048

#define PHI_BYTES ((size_t)8 * 32 * 8192 * 2)            // 4 MB bf16 phiT (no w fold)
#define GATES_OFF PHI_BYTES                              // float[4096][32] = 512 KB
#define WS_NEED   (GATES_OFF + (size_t)TOKS * 32 * 4)

typedef __attribute__((ext_vector_type(8))) short bf16x8;
typedef __attribute__((ext_vector_type(4))) float f32x4;

__device__ __forceinline__ unsigned short f2bf(float f) {
  unsigned int u = __float_as_uint(f);
  u += 0x7FFFu + ((u >> 16) & 1u);
  return (unsigned short)(u >> 16);
}
__device__ __forceinline__ float bf2f(unsigned short s) {
  return __uint_as_float(((unsigned int)s) << 16);
}
__device__ __forceinline__ unsigned int pack2(float a, float b) {
  return (unsigned int)f2bf(a) | ((unsigned int)f2bf(b) << 16);
}

// ---------------- K0 v2: COALESCED transpose phi -> phiT (bf16, [A][32][8192]) ----------------
// rows 0-3 = pre cols, 4-7 = post cols, 8-23 = res cols, 24-31 = zero.
// Thread owns e0 = 2*gid..+1: reads are contiguous float4 runs (full cacheline use);
// writes are ushort2 per r-row -> 256 B contiguous per wave per row.
__global__ __launch_bounds__(256)
void prep_phiT(const float* __restrict__ pre, const float* __restrict__ post,
               const float* __restrict__ res, unsigned short* __restrict__ phiT) {
  const int gid = blockIdx.x * 256 + threadIdx.x;    // 8 * 4096 threads
  const int a = gid >> 12;
  const int e0 = (gid & 4095) * 2;

  // pre[e][0..3], e = e0, e0+1  (contiguous 32 B per thread)
  const float4 p0 = *(const float4*)(pre + ((size_t)a * NCF + e0) * 4);
  const float4 p1 = *(const float4*)(pre + ((size_t)a * NCF + e0) * 4 + 4);
  const float4 q0 = *(const float4*)(post + ((size_t)a * NCF + e0) * 4);
  const float4 q1 = *(const float4*)(post + ((size_t)a * NCF + e0) * 4 + 4);
  // res[e][0..15], e = e0, e0+1  (contiguous 128 B per thread)
  float r0[16], r1[16];
  #pragma unroll
  for (int j = 0; j < 4; ++j) {
    const float4 v = *(const float4*)(res + ((size_t)a * NCF + e0) * 16 + j * 4);
    r0[j*4+0] = v.x; r0[j*4+1] = v.y; r0[j*4+2] = v.z; r0[j*4+3] = v.w;
  }
  #pragma unroll
  for (int j = 0; j < 4; ++j) {
    const float4 v = *(const float4*)(res + ((size_t)a * NCF + e0) * 16 + 16 + j * 4);
    r1[j*4+0] = v.x; r1[j*4+1] = v.y; r1[j*4+2] = v.z; r1[j*4+3] = v.w;
  }

  unsigned short* base = phiT + (size_t)a * 32 * NCF + e0;
  const float pr0[4] = { p0.x, p0.y, p0.z, p0.w };
  const float pr1[4] = { p1.x, p1.y, p1.z, p1.w };
  const float po0[4] = { q0.x, q0.y, q0.z, q0.w };
  const float po1[4] = { q1.x, q1.y, q1.z, q1.w };
  #pragma unroll
  for (int r = 0; r < 4; ++r)
    *(unsigned int*)(base + (size_t)r * NCF) = pack2(pr0[r], pr1[r]);
  #pragma unroll
  for (int r = 0; r < 4; ++r)
    *(unsigned int*)(base + (size_t)(4 + r) * NCF) = pack2(po0[r], po1[r]);
  #pragma unroll
  for (int r = 0; r < 16; ++r)
    *(unsigned int*)(base + (size_t)(8 + r) * NCF) = pack2(r0[r], r1[r]);
  #pragma unroll
  for (int r = 24; r < 32; ++r)
    *(unsigned int*)(base + (size_t)r * NCF) = 0u;
}

// ---------------- K1: logits via MFMA + rms + sigmoid + Sinkhorn -> gates[tok][32] [r6-proven verbatim]
// 512 threads = 8 waves; wave w owns K-slice [w*1024, (w+1)*1024) for a 16-token tile.
__global__ __launch_bounds__(512, 1)
void logits_gates(const float* __restrict__ x,
                  const float* __restrict__ wnorm,
                  const unsigned short* __restrict__ phiT,
                  const float* __restrict__ b_pre, const float* __restrict__ b_post,
                  const float* __restrict__ b_res,
                  const float* __restrict__ a_pre, const float* __restrict__ a_post,
                  const float* __restrict__ a_res,
                  const int* __restrict__ aidx_arr,
                  float* __restrict__ gates) {
  __shared__ unsigned short xs[8][16 * 264];   // per-wave bf16 tile [16 tok][256 feat], row pad 264
  __shared__ float logits_s[8][16][32];
  __shared__ float ssq_s[8][16];

  const int tid = threadIdx.x;
  const int wave = tid >> 6, lane = tid & 63;
  const int tok0 = blockIdx.x * 16;
  const int aidx = aidx_arr[tok0 >> 10];
  const int kbase = wave * 1024;

  const float* xbase = x + (size_t)tok0 * NCF + kbase + lane * 4;
  const float* wbase = wnorm + (size_t)aidx * NCF + kbase + lane * 4;
  const unsigned short* pBbase =
      phiT + ((size_t)aidx * 32 + (lane & 15)) * NCF + kbase + (lane >> 4) * 8;

  f32x4 acc0 = {0.f, 0.f, 0.f, 0.f};
  f32x4 acc1 = {0.f, 0.f, 0.f, 0.f};
  float ssq[16];
  #pragma unroll
  for (int r = 0; r < 16; ++r) ssq[r] = 0.f;

  float4 xr[16];
  #pragma unroll
  for (int r = 0; r < 16; ++r) xr[r] = *(const float4*)(xbase + (size_t)r * NCF);

  for (int t = 0; t < 4; ++t) {
    const float4 wv = *(const float4*)(wbase + t * 256);
    // stage: ssq + bf16(w*x) -> LDS (wave-private, no barrier needed)
    #pragma unroll
    for (int r = 0; r < 16; ++r) {
      const float4 xv = xr[r];
      ssq[r] += xv.x * xv.x + xv.y * xv.y + xv.z * xv.z + xv.w * xv.w;
      ushort4 u = make_ushort4(f2bf(xv.x * wv.x), f2bf(xv.y * wv.y),
                               f2bf(xv.z * wv.z), f2bf(xv.w * wv.w));
      *(ushort4*)&xs[wave][r * 264 + lane * 4] = u;
    }
    if (t < 3) {
      #pragma unroll
      for (int r = 0; r < 16; ++r)
        xr[r] = *(const float4*)(xbase + (size_t)r * NCF + (t + 1) * 256);
    }
    const unsigned short* pB = pBbase + t * 256;
    #pragma unroll
    for (int s = 0; s < 8; ++s) {
      bf16x8 a = *(const bf16x8*)&xs[wave][(lane & 15) * 264 + s * 32 + (lane >> 4) * 8];
      bf16x8 b0 = *(const bf16x8*)(pB + s * 32);
      bf16x8 b1 = *(const bf16x8*)(pB + 16 * NCF + s * 32);
      acc0 = __builtin_amdgcn_mfma_f32_16x16x32_bf16(a, b0, acc0, 0, 0, 0);
      acc1 = __builtin_amdgcn_mfma_f32_16x16x32_bf16(a, b1, acc1, 0, 0, 0);
    }
  }

  // ssq reduce across 64 lanes
  #pragma unroll
  for (int r = 0; r < 16; ++r) {
    float v = ssq[r];
    #pragma unroll
    for (int m = 1; m <= 32; m <<= 1) v += __shfl_xor(v, m, 64);
    if (lane == 0) ssq_s[wave][r] = v;
  }
  // C frags -> LDS: D[m=tok][n=col], m=(lane>>4)*4+i, n=lane&15
  #pragma unroll
  for (int i = 0; i < 4; ++i) {
    logits_s[wave][(lane >> 4) * 4 + i][lane & 15] = acc0[i];
    logits_s[wave][(lane >> 4) * 4 + i][16 + (lane & 15)] = acc1[i];
  }
  __syncthreads();

  if (tid < 256) {
    // per-thread: tok = tid>>4 (0..15), cl = tid&15
    const int tok = tid >> 4, cl = tid & 15;
    float L0 = 0.f, L16 = 0.f, ssqt = 0.f;
    #pragma unroll
    for (int w = 0; w < 8; ++w) {
      L0 += logits_s[w][tok][cl];
      L16 += logits_s[w][tok][16 + cl];
      ssqt += ssq_s[w][tok];
    }
    const float invr = rsqrtf(ssqt * (1.f / NCF) + EPS);

    float* g = gates + (size_t)(tok0 + tok) * 32;
    if (cl < 4) {
      const float zp = a_pre[aidx] * L0 * invr + b_pre[(size_t)aidx * 4 + cl];
      g[cl] = 1.f / (1.f + __expf(-zp));
    } else if (cl < 8) {
      const float zq = a_post[aidx] * L0 * invr + b_post[(size_t)aidx * 4 + (cl - 4)];
      g[cl] = 2.f / (1.f + __expf(-zq));
    }
    // gather res logits: res[cl] = col 8+cl
    const float resv = __shfl_xor((cl & 8) ? L0 : L16, 8, 64);
    const float tl = a_res[aidx] * resv * invr + b_res[(size_t)aidx * 16 + cl];
    float m = __expf(tl);
    #pragma unroll
    for (int it = 0; it < 20; ++it) {
      float rs = m;
      rs += __shfl_xor(rs, 1, 64);
      rs += __shfl_xor(rs, 2, 64);
      m *= __builtin_amdgcn_rcpf(rs);
      float cs = m;
      cs += __shfl_xor(cs, 4, 64);
      cs += __shfl_xor(cs, 8, 64);
      m *= __builtin_amdgcn_rcpf(cs);
    }
    g[8 + cl] = m;
  }
}

// ---------------- K3: streaming output pass  [r6-proven verbatim] ----------------
__global__ __launch_bounds__(256)
void out_pass(const float* __restrict__ x, const float* __restrict__ outp,
              const float* __restrict__ gates,
              float* __restrict__ agg, float* __restrict__ big) {
  const int tok = blockIdx.x;
  const int tid = threadIdx.x;
  const float* g = gates + (size_t)tok * 32;
  float hp[4], hq[4], M[16];
  #pragma unroll
  for (int i = 0; i < 4; ++i) { hp[i] = g[i]; hq[i] = g[4 + i]; }
  #pragma unroll
  for (int i = 0; i < 16; ++i) M[i] = g[8 + i];

  const float* xrow = x + (size_t)tok * NCF;
  const float* orow = outp + (size_t)tok * CCH;
  float* arow = agg + (size_t)tok * CCH;
  float* brow = big + (size_t)tok * NCF;

  #pragma unroll
  for (int rep = 0; rep < 2; ++rep) {
    const int c = rep * 1024 + tid * 4;
    float4 xv[4];
    #pragma unroll
    for (int j = 0; j < 4; ++j) xv[j] = *(const float4*)(xrow + j * CCH + c);
    const float4 ov = *(const float4*)(orow + c);

    f32x4 ag;
    ag.x = hp[0]*xv[0].x + hp[1]*xv[1].x + hp[2]*xv[2].x + hp[3]*xv[3].x;
    ag.y = hp[0]*xv[0].y + hp[1]*xv[1].y + hp[2]*xv[2].y + hp[3]*xv[3].y;
    ag.z = hp[0]*xv[0].z + hp[1]*xv[1].z + hp[2]*xv[2].z + hp[3]*xv[3].z;
    ag.w = hp[0]*xv[0].w + hp[1]*xv[1].w + hp[2]*xv[2].w + hp[3]*xv[3].w;
    __builtin_nontemporal_store(ag, (f32x4*)(arow + c));

    #pragma unroll
    for (int i = 0; i < 4; ++i) {
      const float m0 = M[i*4+0], m1 = M[i*4+1], m2 = M[i*4+2], m3 = M[i*4+3];
      f32x4 o;
      o.x = m0*xv[0].x + m1*xv[1].x + m2*xv[2].x + m3*xv[3].x + hq[i]*ov.x;
      o.y = m0*xv[0].y + m1*xv[1].y + m2*xv[2].y + m3*xv[3].y + hq[i]*ov.y;
      o.z = m0*xv[0].z + m1*xv[1].z + m2*xv[2].z + m3*xv[3].z + hq[i]*ov.z;
      o.w = m0*xv[0].w + m1*xv[1].w + m2*xv[2].w + m3*xv[3].w + hq[i]*ov.w;
      __builtin_nontemporal_store(o, (f32x4*)(brow + i * CCH + c));
    }
  }
}

// ---------------- fallback: round-1 fused kernel (used if ws too small) ----------------
__global__ __launch_bounds__(256, 4)
void lora_fused(const float* __restrict__ x, const float* __restrict__ outp,
                const float* __restrict__ wnorm, const float* __restrict__ phi_pre,
                const float* __restrict__ phi_post, const float* __restrict__ phi_res,
                const float* __restrict__ b_pre, const float* __restrict__ b_post,
                const float* __restrict__ b_res, const float* __restrict__ a_pre,
                const float* __restrict__ a_post, const float* __restrict__ a_res,
                const int* __restrict__ aidx_arr, float* __restrict__ agg_out,
                float* __restrict__ big_out) {
  __shared__ unsigned short xsb[2][NCF];
  __shared__ float scratch[4][52];
  __shared__ float red[52];
  __shared__ float Hpre[2][4], Hpost[2][4], Msm[2][16];
  const int tid = threadIdx.x;
  const int tok0 = blockIdx.x * 2;
  const int aidx = aidx_arr[tok0 >> 10];
  const float* xr0 = x + (size_t)tok0 * NCF;
  const float* xr1 = xr0 + NCF;
  const float* wr = wnorm + (size_t)aidx * NCF;
  const float* pp = phi_pre + (size_t)aidx * NCF * 4;
  const float* pq = phi_post + (size_t)aidx * NCF * 4;
  const float* pr = phi_res + (size_t)aidx * NCF * 16;
  float acc[50];
  #pragma unroll
  for (int i = 0; i < 50; ++i) acc[i] = 0.f;
  for (int k = 0; k < 8; ++k) {
    const int f0 = (k * 256 + tid) * 4;
    const float4 w4 = *(const float4*)(wr + f0);
    const float4 xa = *(const float4*)(xr0 + f0);
    const float4 xb = *(const float4*)(xr1 + f0);
    acc[0] += xa.x*xa.x + xa.y*xa.y + xa.z*xa.z + xa.w*xa.w;
    acc[25] += xb.x*xb.x + xb.y*xb.y + xb.z*xb.z + xb.w*xb.w;
    float xw0[4] = { xa.x*w4.x, xa.y*w4.y, xa.z*w4.z, xa.w*w4.w };
    float xw1[4] = { xb.x*w4.x, xb.y*w4.y, xb.z*w4.z, xb.w*w4.w };
    *(ushort4*)&xsb[0][f0] = make_ushort4(f2bf(xa.x), f2bf(xa.y), f2bf(xa.z), f2bf(xa.w));
    *(ushort4*)&xsb[1][f0] = make_ushort4(f2bf(xb.x), f2bf(xb.y), f2bf(xb.z), f2bf(xb.w));
    #pragma unroll
    for (int d = 0; d < 4; ++d) {
      const int f = f0 + d;
      const float a0 = xw0[d], a1 = xw1[d];
      float col[24];
      const float4 P = *(const float4*)(pp + ((size_t)f << 2));
      const float4 Q = *(const float4*)(pq + ((size_t)f << 2));
      const float4 R0 = *(const float4*)(pr + ((size_t)f << 4));
      const float4 R1 = *(const float4*)(pr + ((size_t)f << 4) + 4);
      const float4 R2 = *(const float4*)(pr + ((size_t)f << 4) + 8);
      const float4 R3 = *(const float4*)(pr + ((size_t)f << 4) + 12);
      col[0]=P.x; col[1]=P.y; col[2]=P.z; col[3]=P.w;
      col[4]=Q.x; col[5]=Q.y; col[6]=Q.z; col[7]=Q.w;
      col[8]=R0.x; col[9]=R0.y; col[10]=R0.z; col[11]=R0.w;
      col[12]=R1.x; col[13]=R1.y; col[14]=R1.z; col[15]=R1.w;
      col[16]=R2.x; col[17]=R2.y; col[18]=R2.z; col[19]=R2.w;
      col[20]=R3.x; col[21]=R3.y; col[22]=R3.z; col[23]=R3.w;
      #pragma unroll
      for (int c = 0; c < 24; ++c) { acc[1 + c] += a0 * col[c]; acc[26 + c] += a1 * col[c]; }
    }
  }
  #pragma unroll
  for (int m = 1; m <= 32; m <<= 1) {
    #pragma unroll
    for (int v = 0; v < 50; ++v) acc[v] += __shfl_xor(acc[v], m, 64);
  }
  const int wave = tid >> 6, lane = tid & 63;
  if (lane == 0) {
    #pragma unroll
    for (int v = 0; v < 50; ++v) scratch[wave][v] = acc[v];
  }
  __syncthreads();
  if (tid < 50) red[tid] = scratch[0][tid] + scratch[1][tid] + scratch[2][tid] + scratch[3][tid];
  __syncthreads();
  if (tid < 32) {
    const int t = tid >> 4, l = tid & 15;
    const float invr = rsqrtf(red[t * 25] * (1.f / NCF) + EPS);
    const float tl = a_res[aidx] * red[t * 25 + 1 + 8 + l] * invr + b_res[(size_t)aidx * 16 + l];
    float m = __expf(tl);
    #pragma unroll
    for (int it = 0; it < 20; ++it) {
      float rs = m; rs += __shfl_xor(rs, 1, 64); rs += __shfl_xor(rs, 2, 64);
      m *= __builtin_amdgcn_rcpf(rs);
      float cs = m; cs += __shfl_xor(cs, 4, 64); cs += __shfl_xor(cs, 8, 64);
      m *= __builtin_amdgcn_rcpf(cs);
    }
    Msm[t][l] = m;
  } else if (tid < 40) {
    const int q = tid - 32, t = q >> 2, n = q & 3;
    const float invr = rsqrtf(red[t * 25] * (1.f / NCF) + EPS);
    const float zp = a_pre[aidx] * red[t * 25 + 1 + n] * invr + b_pre[(size_t)aidx * 4 + n];
    const float zq = a_post[aidx] * red[t * 25 + 1 + 4 + n] * invr + b_post[(size_t)aidx * 4 + n];
    Hpre[t][n] = 1.f / (1.f + __expf(-zp));
    Hpost[t][n] = 2.f / (1.f + __expf(-zq));
  }
  __syncthreads();
  #pragma unroll
  for (int t = 0; t < 2; ++t) {
    const int tok = tok0 + t;
    const float* orow = outp + (size_t)tok * CCH;
    float* arow = agg_out + (size_t)tok * CCH;
    float* brow = big_out + (size_t)tok * 4 * CCH;
    const float hp0 = Hpre[t][0], hp1 = Hpre[t][1], hp2 = Hpre[t][2], hp3 = Hpre[t][3];
    float Mr[16];
    #pragma unroll
    for (int i = 0; i < 16; ++i) Mr[i] = Msm[t][i];
    const float hq[4] = { Hpost[t][0], Hpost[t][1], Hpost[t][2], Hpost[t][3] };
    #pragma unroll
    for (int w = 0; w < 2; ++w) {
      const int c0 = (w * 256 + tid) * 4;
      float4 xv[4];
      #pragma unroll
      for (int n = 0; n < 4; ++n) {
        const ushort4 u = *(const ushort4*)&xsb[t][n * CCH + c0];
        xv[n] = make_float4(bf2f(u.x), bf2f(u.y), bf2f(u.z), bf2f(u.w));
      }
      const float4 ov = *(const float4*)(orow + c0);
      float4 ag;
      ag.x = hp0*xv[0].x + hp1*xv[1].x + hp2*xv[2].x + hp3*xv[3].x;
      ag.y = hp0*xv[0].y + hp1*xv[1].y + hp2*xv[2].y + hp3*xv[3].y;
      ag.z = hp0*xv[0].z + hp1*xv[1].z + hp2*xv[2].z + hp3*xv[3].z;
      ag.w = hp0*xv[0].w + hp1*xv[1].w + hp2*xv[2].w + hp3*xv[3].w;
      *(float4*)(arow + c0) = ag;
      #pragma unroll
      for (int i = 0; i < 4; ++i) {
        const float m0 = Mr[i*4+0], m1 = Mr[i*4+1], m2 = Mr[i*4+2], m3 = Mr[i*4+3];
        float4 o;
        o.x = m0*xv[0].x + m1*xv[1].x + m2*xv[2].x + m3*xv[3].x + hq[i]*ov.x;
        o.y = m0*xv[0].y + m1*xv[1].y + m2*xv[2].y + m3*xv[3].y + hq[i]*ov.y;
        o.z = m0*xv[0].z + m1*xv[1].z + m2*xv[2].z + m3*xv[3].z + hq[i]*ov.z;
        o.w = m0*xv[0].w + m1*xv[1].w + m2*xv[2].w + m3*xv[3].w + hq[i]*ov.w;
        *(float4*)(brow + (size_t)i * CCH + c0) = o;
      }
    }
  }
}

extern "C" void kernel_launch(void* const* d_in, const int* in_sizes, int n_in,
                              void* d_out, int out_size, void* d_ws, size_t ws_size,
                              hipStream_t stream) {
  const float* x     = (const float*)d_in[0];
  const float* outp  = (const float*)d_in[1];
  const float* wnorm = (const float*)d_in[2];
  const float* ppre  = (const float*)d_in[3];
  const float* ppost = (const float*)d_in[4];
  const float* pres  = (const float*)d_in[5];
  const float* bpre  = (const float*)d_in[6];
  const float* bpost = (const float*)d_in[7];
  const float* bres  = (const float*)d_in[8];
  const float* apre  = (const float*)d_in[9];
  const float* apost = (const float*)d_in[10];
  const float* ares  = (const float*)d_in[11];
  const int*   aidx  = (const int*)d_in[12];

  float* agg = (float*)d_out;
  float* big = (float*)d_out + (size_t)TOKS * CCH;

  if (ws_size >= WS_NEED) {
    unsigned short* phiT = (unsigned short*)d_ws;
    float* gates = (float*)((char*)d_ws + GATES_OFF);
    hipLaunchKernelGGL(prep_phiT, dim3(128), dim3(256), 0, stream,
                       ppre, ppost, pres, phiT);
    hipLaunchKernelGGL(logits_gates, dim3(256), dim3(512), 0, stream,
                       x, wnorm, phiT, bpre, bpost, bres, apre, apost, ares, aidx, gates);
    hipLaunchKernelGGL(out_pass, dim3(4096), dim3(256), 0, stream, x, outp, gates, agg, big);
  } else {
    hipLaunchKernelGGL(lora_fused, dim3(2048), dim3(256), 0, stream,
                       x, outp, wnorm, ppre, ppost, pres,
                       bpre, bpost, bres, apre, apost, ares, aidx, agg, big);
  }
}